// Round 4
// baseline (264.145 us; speedup 1.0000x reference)
//
#include <hip/hip_runtime.h>

typedef unsigned short u16;
typedef unsigned int   u32;
typedef __attribute__((ext_vector_type(8))) short bf16x8;
typedef __attribute__((ext_vector_type(4))) float f32x4;

#define SEQ 1024
#define BSZ 8
#define EMB 1024
#define NH  16
#define DH  64
#define KVB 64

__device__ __forceinline__ u16 f2bf(float f) {
    u32 u = __float_as_uint(f);
    u32 r = u + 0x7FFFu + ((u >> 16) & 1u);   // round-to-nearest-even
    return (u16)(r >> 16);
}

#define GLDS16(g, l) __builtin_amdgcn_global_load_lds( \
    (const __attribute__((address_space(1))) void*)(g), \
    (__attribute__((address_space(3))) void*)(l), 16, 0, 0)

// ---------------- convert x (fp32) -> xb (bf16) ----------------
__global__ __launch_bounds__(256) void cvt_x_k(const float* __restrict__ x,
                                               u16* __restrict__ xb) {
    size_t i = ((size_t)blockIdx.x * 256 + threadIdx.x) * 8;
    float4 a = *reinterpret_cast<const float4*>(x + i);
    float4 b = *reinterpret_cast<const float4*>(x + i + 4);
    union { u16 u[8]; uint4 v; } o;
    o.u[0]=f2bf(a.x); o.u[1]=f2bf(a.y); o.u[2]=f2bf(a.z); o.u[3]=f2bf(a.w);
    o.u[4]=f2bf(b.x); o.u[5]=f2bf(b.y); o.u[6]=f2bf(b.z); o.u[7]=f2bf(b.w);
    *reinterpret_cast<uint4*>(xb + i) = o.v;
}

// ------- convert + transpose weights: w (K,N) fp32 -> wT (N,K) bf16 -------
__global__ __launch_bounds__(256) void cvt_w_k(const float* __restrict__ w0, const float* __restrict__ w1,
                                               const float* __restrict__ w2, const float* __restrict__ w3,
                                               u16* __restrict__ wT) {
    int id  = blockIdx.x * 256 + threadIdx.x;
    int wi  = id >> 17;
    int rem = id & 131071;
    int kc  = rem >> 10;
    int n   = rem & 1023;
    const float* src = (wi==0) ? w0 : (wi==1) ? w1 : (wi==2) ? w2 : w3;
    union { u16 u[8]; uint4 v; } o;
    #pragma unroll
    for (int i = 0; i < 8; ++i) o.u[i] = f2bf(src[(size_t)(kc*8+i)*1024 + n]);
    *reinterpret_cast<uint4*>(wT + (size_t)wi*1048576 + (size_t)n*1024 + kc*8) = o.v;
}

// ---------------- bf16 GEMM, C = A(M,K) * BT(N,K)^T ----------------
// 3-deep GLDS pipeline, counted vmcnt across raw s_barrier, (r>>1)&3 chunk swizzle.
template<int MODE>
__global__ __launch_bounds__(256) void gemm_bt(
    const u16* __restrict__ A, const u16* __restrict__ BT,
    const float* __restrict__ xres, const float* __restrict__ bias,
    u16* __restrict__ qh, u16* __restrict__ kh, u16* __restrict__ vh,
    float* __restrict__ outp)
{
    __shared__ u16 As[3][128*32];
    __shared__ u16 Bs[3][128*32];

    const int tid  = threadIdx.x;
    const int lane = tid & 63;
    const int wv   = tid >> 6;
    const int wm   = wv >> 1, wn = wv & 1;

    // XCD-bijective remap of the flat workgroup id (nwg % 8 == 0)
    const int nwg  = gridDim.x * gridDim.y * gridDim.z;
    const int flat = blockIdx.x + gridDim.x * (blockIdx.y + gridDim.y * blockIdx.z);
    const int rid  = (flat & 7) * (nwg >> 3) + (flat >> 3);
    const int nBlk = rid & 7;
    const int mBlk = (rid >> 3) & 63;
    const int z    = (MODE == 0) ? (rid >> 9) : 0;

    const int mBase = mBlk * 128;
    const int nBase = nBlk * 128;
    const u16* Bm = BT + (size_t)z * (1024*1024);

    // staging: thread tid owns LDS 16B chunks tid and tid+256 (linear dest);
    // global source chunk XOR-swizzled by (row>>1)&3 (read side applies same XOR)
    const int r0  = tid >> 2;
    const int cb0 = (tid & 3) ^ ((r0 >> 1) & 3);
    const u16* Ap0 = A  + (size_t)(mBase + r0)      * 1024 + cb0*8;
    const u16* Ap1 = A  + (size_t)(mBase + r0 + 64) * 1024 + cb0*8;   // ((r0+64)>>1)&3 == (r0>>1)&3
    const u16* Bp0 = Bm + (size_t)(nBase + r0)      * 1024 + cb0*8;
    const u16* Bp1 = Bm + (size_t)(nBase + r0 + 64) * 1024 + cb0*8;
    const int wb = wv * 512;

    f32x4 acc[4][4];
    #pragma unroll
    for (int i = 0; i < 4; ++i)
        #pragma unroll
        for (int j = 0; j < 4; ++j) acc[i][j] = (f32x4){0.f,0.f,0.f,0.f};

    const int arow = wm*64 + (lane & 15);
    const int brow = wn*64 + (lane & 15);
    const int kby  = (lane >> 4) * 16;
    const int aswz = ((arow >> 1) & 3) << 4;   // (arow+16f)>>1 & 3 invariant in f
    const int bswz = ((brow >> 1) & 3) << 4;

    auto stg = [&](int buf, int kt) {
        const int ko = kt * 32;
        GLDS16(Ap0 + ko, &As[buf][wb]);
        GLDS16(Ap1 + ko, &As[buf][wb + 2048]);
        GLDS16(Bp0 + ko, &Bs[buf][wb]);
        GLDS16(Bp1 + ko, &Bs[buf][wb + 2048]);
    };

    auto compute = [&](int buf) {
        bf16x8 af[4], bf[4];
        #pragma unroll
        for (int f = 0; f < 4; ++f)
            af[f] = *reinterpret_cast<const bf16x8*>(
                reinterpret_cast<const char*>(&As[buf][(arow + f*16)*32]) + (kby ^ aswz));
        #pragma unroll
        for (int f = 0; f < 4; ++f)
            bf[f] = *reinterpret_cast<const bf16x8*>(
                reinterpret_cast<const char*>(&Bs[buf][(brow + f*16)*32]) + (kby ^ bswz));
        #pragma unroll
        for (int i = 0; i < 4; ++i)
            #pragma unroll
            for (int j = 0; j < 4; ++j)
                acc[i][j] = __builtin_amdgcn_mfma_f32_16x16x32_bf16(af[i], bf[j], acc[i][j], 0, 0, 0);
    };

    const int NT = 1024 / 32;      // 32 K-steps
    stg(0, 0);
    stg(1, 1);
    for (int kt = 0; kt < NT - 1; ++kt) {
        // my 4 oldest loads (buf kt%3) done; 4 newer (kt+1) stay in flight
        asm volatile("s_waitcnt vmcnt(4) lgkmcnt(0)" ::: "memory");
        __builtin_amdgcn_sched_barrier(0);
        __builtin_amdgcn_s_barrier();
        __builtin_amdgcn_sched_barrier(0);
        if (kt + 2 < NT) stg((kt + 2) % 3, kt + 2);
        compute(kt % 3);
    }
    asm volatile("s_waitcnt vmcnt(0) lgkmcnt(0)" ::: "memory");
    __builtin_amdgcn_sched_barrier(0);
    __builtin_amdgcn_s_barrier();
    __builtin_amdgcn_sched_barrier(0);
    compute((NT - 1) % 3);

    // epilogue: C layout col=lane&15, row=(lane>>4)*4+reg
    const int rbase = (lane >> 4) * 4;
    const int cbase = lane & 15;
    #pragma unroll
    for (int i = 0; i < 4; ++i) {
        #pragma unroll
        for (int j = 0; j < 4; ++j) {
            #pragma unroll
            for (int r = 0; r < 4; ++r) {
                const int m = mBase + wm*64 + i*16 + rbase + r;
                const int n = nBase + wn*64 + j*16 + cbase;
                const float v = acc[i][j][r];
                if (MODE == 0) {
                    const int s = m >> 3, bb = m & 7;
                    const int h = n >> 6, d  = n & 63;
                    const size_t oidx = ((size_t)(bb*NH + h)*SEQ + s)*DH + d;
                    if (z == 0)      qh[oidx] = f2bf(v * 0.125f);
                    else if (z == 1) kh[oidx] = f2bf(v);
                    else             vh[oidx] = f2bf(v + xres[(size_t)m*1024 + n]);
                } else {
                    outp[(size_t)m*1024 + n] = v + bias[n];
                }
            }
        }
    }
}

// ---------------- transpose V: vh[bh][s][d] -> vt[bh][d][s] ----------------
__global__ __launch_bounds__(256) void vtrans_k(const u16* __restrict__ vh,
                                                u16* __restrict__ vt) {
    __shared__ u16 T[64*64];
    const int tid = threadIdx.x;
    const int s0 = blockIdx.x * 64;
    const size_t base = (size_t)blockIdx.y * (SEQ*DH);
    #pragma unroll
    for (int k = 0; k < 2; ++k) {
        const int idx = k*256 + tid;
        const int r = idx >> 3, c = idx & 7;
        uint4 v = *reinterpret_cast<const uint4*>(vh + base + (size_t)(s0 + r)*DH + c*8);
        const int cs = c ^ (r & 7) ^ ((r >> 3) & 7);
        *reinterpret_cast<uint4*>(reinterpret_cast<char*>(T) + r*128 + cs*16) = v;
    }
    __syncthreads();
    #pragma unroll
    for (int k = 0; k < 2; ++k) {
        const int idx = k*256 + tid;
        const int d = idx >> 3, kc = idx & 7;
        union { u16 u[8]; uint4 v; } o;
        #pragma unroll
        for (int i = 0; i < 8; ++i) {
            const int s = kc*8 + i;
            const int ch = (d >> 3) ^ (s & 7) ^ ((s >> 3) & 7);
            o.u[i] = T[s*64 + ch*8 + (d & 7)];
        }
        *reinterpret_cast<uint4*>(vt + base + (size_t)d*SEQ + s0 + kc*8) = o.v;
    }
}

// ---------------- flash attention: LDS-staged K/V (GLDS16 + swizzle) ----------------
// block = 4 waves x 32 q-rows = 128 q; grid (8, 128), XCD-remapped inside
__global__ __launch_bounds__(256, 2) void attn_k(
    const u16* __restrict__ qh, const u16* __restrict__ kh,
    const u16* __restrict__ vt, const float* __restrict__ mask,
    u16* __restrict__ ctx)
{
    __shared__ u16 Kl[2][KVB*64];   // [key][d], chunk-swizzled by key&7
    __shared__ u16 Vl[2][KVB*64];   // [d][key], chunk-swizzled by d&7
    __shared__ u16 Pl[128*64];      // [q][key], chunk-swizzled by q&7

    const int tid  = threadIdx.x;
    const int lane = tid & 63;
    const int wv   = tid >> 6;
    const int l15  = lane & 15;
    const int lg   = lane >> 4;

    // XCD remap: dispatch id d0, xcd = d0&7 owns bh in [xcd*16, xcd*16+16)
    const int d0 = blockIdx.y * 8 + blockIdx.x;
    const int bh = (d0 & 7) * 16 + (d0 >> 6);
    const int qt = (d0 >> 3) & 7;
    const int b  = bh >> 4;
    const int h  = bh & 15;
    const int qbase = qt * 128;
    const size_t bhOff = (size_t)bh * (SEQ*DH);

    // staging geometry: chunk idx = s*256+tid; row r = idx>>3, chunk c = idx&7
    const int rS = tid >> 3;                    // 0..31 (s=0); +32 for s=1
    const int cS = (tid & 7) ^ (rS & 7);        // pre-swizzled source chunk
    const u16* kSrc = kh + bhOff + (size_t)rS*DH  + cS*8;
    const u16* vSrc = vt + bhOff + (size_t)rS*SEQ + cS*8;
    const int ldst = wv * 512;                  // u16 offset of wave segment

    // Q fragments: aq[fq][kk]
    bf16x8 aq[2][2];
    #pragma unroll
    for (int fq = 0; fq < 2; ++fq)
        #pragma unroll
        for (int kk = 0; kk < 2; ++kk)
            aq[fq][kk] = *reinterpret_cast<const bf16x8*>(
                qh + bhOff + (size_t)(qbase + wv*32 + fq*16 + l15)*DH + kk*32 + lg*8);

    f32x4 o[2][4];
    float mrun[2][4], lrun[2][4];
    #pragma unroll
    for (int fq = 0; fq < 2; ++fq) {
        #pragma unroll
        for (int fd = 0; fd < 4; ++fd) o[fq][fd] = (f32x4){0.f,0.f,0.f,0.f};
        #pragma unroll
        for (int j = 0; j < 4; ++j) { mrun[fq][j] = -1e30f; lrun[fq][j] = 0.f; }
    }

    bf16x8 ones;
    #pragma unroll
    for (int i = 0; i < 8; ++i) ones[i] = (short)0x3F80;

    // fragment read chunk-offsets (bytes): chunk = (kk*4+lg) ^ (row&7), row&7 == l15&7
    const int co0 = ((lg)     ^ (l15 & 7)) << 4;
    const int co1 = ((4 + lg) ^ (l15 & 7)) << 4;
    const float* mPtr = mask + (size_t)b*SEQ + l15;
    const int pq = wv*32;

    auto stage = [&](int buf, int kt) {
        const int jb = kt * KVB;
        GLDS16(kSrc + (size_t)jb*DH,        &Kl[buf][ldst]);
        GLDS16(kSrc + (size_t)(jb+32)*DH,   &Kl[buf][2048 + ldst]);
        GLDS16(vSrc + jb,                   &Vl[buf][ldst]);
        GLDS16(vSrc + 32*SEQ + jb,          &Vl[buf][2048 + ldst]);
    };

    stage(0, 0);
    int cur = 0;

    for (int kt = 0; kt < 16; ++kt) {
        __syncthreads();                      // drains stage of buf[cur] + prior reads
        if (kt + 1 < 16) stage(cur ^ 1, kt + 1);
        const int jb = kt * KVB;

        // ---- scores: S = Q * K^T ----
        f32x4 sc[2][4];
        const char* kb = reinterpret_cast<const char*>(&Kl[cur][0]) + l15*128;
        #pragma unroll
        for (int fn = 0; fn < 4; ++fn) {
            bf16x8 k0 = *reinterpret_cast<const bf16x8*>(kb + fn*2048 + co0);
            bf16x8 k1 = *reinterpret_cast<const bf16x8*>(kb + fn*2048 + co1);
            #pragma unroll
            for (int fq = 0; fq < 2; ++fq) {
                f32x4 t = __builtin_amdgcn_mfma_f32_16x16x32_bf16(aq[fq][0], k0,
                            (f32x4){0.f,0.f,0.f,0.f}, 0, 0, 0);
                sc[fq][fn] = __builtin_amdgcn_mfma_f32_16x16x32_bf16(aq[fq][1], k1, t, 0, 0, 0);
            }
        }
        // ---- additive key-padding mask ----
        float mv[4];
        #pragma unroll
        for (int fn = 0; fn < 4; ++fn) mv[fn] = mPtr[jb + fn*16];
        #pragma unroll
        for (int fq = 0; fq < 2; ++fq)
            #pragma unroll
            for (int fn = 0; fn < 4; ++fn)
                #pragma unroll
                for (int j = 0; j < 4; ++j) sc[fq][fn][j] += mv[fn];
        // ---- tile max ----
        float mx[2][4];
        #pragma unroll
        for (int fq = 0; fq < 2; ++fq)
            #pragma unroll
            for (int j = 0; j < 4; ++j)
                mx[fq][j] = fmaxf(fmaxf(sc[fq][0][j], sc[fq][1][j]),
                                  fmaxf(sc[fq][2][j], sc[fq][3][j]));
        #pragma unroll
        for (int off = 1; off < 16; off <<= 1)
            #pragma unroll
            for (int fq = 0; fq < 2; ++fq)
                #pragma unroll
                for (int j = 0; j < 4; ++j)
                    mx[fq][j] = fmaxf(mx[fq][j], __shfl_xor(mx[fq][j], off));
        // ---- defer-max rescale ----
        int need = 0;
        #pragma unroll
        for (int fq = 0; fq < 2; ++fq)
            #pragma unroll
            for (int j = 0; j < 4; ++j)
                need |= (mx[fq][j] > mrun[fq][j] + 8.0f);
        if (__any(need)) {
            #pragma unroll
            for (int fq = 0; fq < 2; ++fq)
                #pragma unroll
                for (int j = 0; j < 4; ++j) {
                    const float mn = fmaxf(mrun[fq][j], mx[fq][j]);
                    const float s  = __expf(mrun[fq][j] - mn);
                    mrun[fq][j] = mn;
                    lrun[fq][j] *= s;
                    #pragma unroll
                    for (int fd = 0; fd < 4; ++fd) o[fq][fd][j] *= s;
                }
        }
        // ---- P = exp(sc - mrun) -> LDS (truncate to bf16; wave-private rows) ----
        #pragma unroll
        for (int fq = 0; fq < 2; ++fq)
            #pragma unroll
            for (int fn = 0; fn < 4; ++fn)
                #pragma unroll
                for (int j = 0; j < 4; ++j) {
                    const float p = __expf(sc[fq][fn][j] - mrun[fq][j]);
                    const int q = pq + fq*16 + lg*4 + j;
                    const int off = (q*128 + (fn*16 + l15)*2) ^ ((q & 7) << 4);
                    *reinterpret_cast<u16*>(reinterpret_cast<char*>(Pl) + off) =
                        (u16)(__float_as_uint(p) >> 16);
                }
        asm volatile("s_waitcnt lgkmcnt(0)" ::: "memory");
        __builtin_amdgcn_sched_barrier(0);
        // ---- P A-fragments back from LDS ----
        bf16x8 pa[2][2];
        #pragma unroll
        for (int fq = 0; fq < 2; ++fq) {
            const int q = pq + fq*16 + l15;
            pa[fq][0] = *reinterpret_cast<const bf16x8*>(
                reinterpret_cast<char*>(Pl) + q*128 + co0);
            pa[fq][1] = *reinterpret_cast<const bf16x8*>(
                reinterpret_cast<char*>(Pl) + q*128 + co1);
        }
        // ---- row-sums via ones-MFMA ----
        #pragma unroll
        for (int fq = 0; fq < 2; ++fq) {
            f32x4 racc = __builtin_amdgcn_mfma_f32_16x16x32_bf16(pa[fq][0], ones,
                            (f32x4){0.f,0.f,0.f,0.f}, 0, 0, 0);
            racc = __builtin_amdgcn_mfma_f32_16x16x32_bf16(pa[fq][1], ones, racc, 0, 0, 0);
            #pragma unroll
            for (int j = 0; j < 4; ++j) lrun[fq][j] += racc[j];
        }
        // ---- O += P * V ----
        const char* vb = reinterpret_cast<const char*>(&Vl[cur][0]) + l15*128;
        #pragma unroll
        for (int fd = 0; fd < 4; ++fd) {
            bf16x8 v0 = *reinterpret_cast<const bf16x8*>(vb + fd*2048 + co0);
            bf16x8 v1 = *reinterpret_cast<const bf16x8*>(vb + fd*2048 + co1);
            #pragma unroll
            for (int fq = 0; fq < 2; ++fq) {
                o[fq][fd] = __builtin_amdgcn_mfma_f32_16x16x32_bf16(pa[fq][0], v0, o[fq][fd], 0, 0, 0);
                o[fq][fd] = __builtin_amdgcn_mfma_f32_16x16x32_bf16(pa[fq][1], v1, o[fq][fd], 0, 0, 0);
            }
        }
        cur ^= 1;
    }

    // ---- epilogue: ctx[(s*B+b)][h*64+d] bf16 ----
    #pragma unroll
    for (int fq = 0; fq < 2; ++fq)
        #pragma unroll
        for (int j = 0; j < 4; ++j) {
            const float inv = 1.0f / lrun[fq][j];
            const int s = qbase + wv*32 + fq*16 + lg*4 + j;
            #pragma unroll
            for (int fd = 0; fd < 4; ++fd) {
                const int d = fd*16 + l15;
                ctx[((size_t)(s*BSZ + b))*EMB + h*DH + d] = f2bf(o[fq][fd][j] * inv);
            }
        }
}

extern "C" void kernel_launch(void* const* d_in, const int* in_sizes, int n_in,
                              void* d_out, int out_size, void* d_ws, size_t ws_size,
                              hipStream_t stream) {
    const float* x    = (const float*)d_in[0];
    const float* mask = (const float*)d_in[1];
    const float* w_q  = (const float*)d_in[2];
    const float* w_k  = (const float*)d_in[3];
    const float* w_v  = (const float*)d_in[4];
    const float* w_o  = (const float*)d_in[5];
    const float* b_o  = (const float*)d_in[6];

    char* ws = (char*)d_ws;
    u16* xb  = (u16*)(ws);                        // 16 MB
    u16* wT  = (u16*)(ws + ((size_t)16 << 20));   // 8 MB
    u16* qh  = (u16*)(ws + ((size_t)24 << 20));   // 16 MB
    u16* kh  = (u16*)(ws + ((size_t)40 << 20));   // 16 MB
    u16* vt  = (u16*)(ws + ((size_t)56 << 20));   // 16 MB (V transposed)
    u16* vh  = (u16*)(ws + ((size_t)72 << 20));   // 16 MB
    u16* ctx = vh;                                // vh dead after vtrans
    float* outp = (float*)d_out;

    cvt_x_k<<<4096, 256, 0, stream>>>(x, xb);
    cvt_w_k<<<2048, 256, 0, stream>>>(w_q, w_k, w_v, w_o, wT);
    gemm_bt<0><<<dim3(8, 64, 3), 256, 0, stream>>>(xb, wT, x, nullptr, qh, kh, vh, nullptr);
    vtrans_k<<<dim3(16, 128), 256, 0, stream>>>(vh, vt);
    attn_k<<<dim3(8, 128), 256, 0, stream>>>(qh, kh, vt, mask, ctx);
    gemm_bt<1><<<dim3(8, 64, 1), 256, 0, stream>>>(ctx, wT + (size_t)3*1048576, nullptr, b_o,
                                                   nullptr, nullptr, nullptr, outp);
}

// Round 5
// 216.307 us; speedup vs baseline: 1.2212x; 1.2212x over previous
//
#include <hip/hip_runtime.h>

typedef unsigned short u16;
typedef unsigned int   u32;
typedef __attribute__((ext_vector_type(8))) short bf16x8;
typedef __attribute__((ext_vector_type(4))) float f32x4;

#define SEQ 1024
#define BSZ 8
#define EMB 1024
#define NH  16
#define DH  64
#define KVB 64

__device__ __forceinline__ u16 f2bf(float f) {
    u32 u = __float_as_uint(f);
    u32 r = u + 0x7FFFu + ((u >> 16) & 1u);   // round-to-nearest-even
    return (u16)(r >> 16);
}
__device__ __forceinline__ float bf2f(u16 u) {
    return __uint_as_float((u32)u << 16);
}

#define GLDS16(g, l) __builtin_amdgcn_global_load_lds( \
    (const __attribute__((address_space(1))) void*)(g), \
    (__attribute__((address_space(3))) void*)(l), 16, 0, 0)

// ------- merged convert: x (fp32)->xb (bf16); w (K,N) fp32 -> wT (N,K) bf16 -------
__global__ __launch_bounds__(256) void cvt_k(
    const float* __restrict__ x, const float* __restrict__ w0,
    const float* __restrict__ w1, const float* __restrict__ w2,
    const float* __restrict__ w3, u16* __restrict__ xb, u16* __restrict__ wT)
{
    const int bid = blockIdx.x;
    if (bid < 4096) {
        size_t i = ((size_t)bid * 256 + threadIdx.x) * 8;
        float4 a = *reinterpret_cast<const float4*>(x + i);
        float4 b = *reinterpret_cast<const float4*>(x + i + 4);
        union { u16 u[8]; uint4 v; } o;
        o.u[0]=f2bf(a.x); o.u[1]=f2bf(a.y); o.u[2]=f2bf(a.z); o.u[3]=f2bf(a.w);
        o.u[4]=f2bf(b.x); o.u[5]=f2bf(b.y); o.u[6]=f2bf(b.z); o.u[7]=f2bf(b.w);
        *reinterpret_cast<uint4*>(xb + i) = o.v;
    } else {
        int id  = (bid - 4096) * 256 + threadIdx.x;
        int wi  = id >> 17;
        int rem = id & 131071;
        int kc  = rem >> 10;
        int n   = rem & 1023;
        const float* src = (wi==0) ? w0 : (wi==1) ? w1 : (wi==2) ? w2 : w3;
        union { u16 u[8]; uint4 v; } o;
        #pragma unroll
        for (int i = 0; i < 8; ++i) o.u[i] = f2bf(src[(size_t)(kc*8+i)*1024 + n]);
        *reinterpret_cast<uint4*>(wT + (size_t)wi*1048576 + (size_t)n*1024 + kc*8) = o.v;
    }
}

// ---------------- bf16 GEMM, C = A(M,K) * BT(N,K)^T ----------------
// m97 structure: 2 LDS buffers, __syncthreads, GLDS w=16 staging; conflict-free
// (r>>1)&3 chunk swizzle; XCD-bijective workgroup remap.
// MODE 0: z selects wq/wk/wv; coalesced head-layout epilogue via LDS bounce.
// MODE 1: out[m][n] = acc + bias[n] (fp32, scalar epilogue).
template<int MODE>
__global__ __launch_bounds__(256) void gemm_bt(
    const u16* __restrict__ A, const u16* __restrict__ BT,
    const float* __restrict__ bias,
    u16* __restrict__ qh, u16* __restrict__ kh, u16* __restrict__ vh,
    float* __restrict__ outp)
{
    __shared__ u16 SH[16384];            // 32KB: As 2x4096 | Bs 2x4096
    u16* Asb = SH;
    u16* Bsb = SH + 8192;

    const int tid  = threadIdx.x;
    const int lane = tid & 63;
    const int wv   = tid >> 6;
    const int wm   = wv >> 1, wn = wv & 1;

    // XCD-bijective remap (nwg % 8 == 0): consecutive rid per XCD
    const int nwg  = gridDim.x * gridDim.y * gridDim.z;
    const int flat = blockIdx.x + gridDim.x * (blockIdx.y + gridDim.y * blockIdx.z);
    const int rid  = (flat & 7) * (nwg >> 3) + (flat >> 3);
    const int nBlk = rid & 7;
    const int mBlk = (rid >> 3) & 63;
    const int z    = (MODE == 0) ? (rid >> 9) : 0;

    const int mBase = mBlk * 128;
    const int nBase = nBlk * 128;
    const u16* Bm = BT + (size_t)z * (1024*1024);

    // staging: thread owns LDS 16B chunks tid, tid+256 (linear dest);
    // global source chunk XOR-swizzled by (row>>1)&3
    const int r0  = tid >> 2;
    const int cb0 = (tid & 3) ^ ((r0 >> 1) & 3);
    const u16* Ap0 = A  + (size_t)(mBase + r0)      * 1024 + cb0*8;
    const u16* Ap1 = A  + (size_t)(mBase + r0 + 64) * 1024 + cb0*8;
    const u16* Bp0 = Bm + (size_t)(nBase + r0)      * 1024 + cb0*8;
    const u16* Bp1 = Bm + (size_t)(nBase + r0 + 64) * 1024 + cb0*8;
    const int wb = wv * 512;

    f32x4 acc[4][4];
    #pragma unroll
    for (int i = 0; i < 4; ++i)
        #pragma unroll
        for (int j = 0; j < 4; ++j) acc[i][j] = (f32x4){0.f,0.f,0.f,0.f};

    const int arow = wm*64 + (lane & 15);
    const int brow = wn*64 + (lane & 15);
    const int kby  = (lane >> 4) * 16;
    const int aswz = ((arow >> 1) & 3) << 4;
    const int bswz = ((brow >> 1) & 3) << 4;

    auto stg = [&](int buf, int kt) {
        const int ko = kt * 32;
        GLDS16(Ap0 + ko, &Asb[buf*4096 + wb]);
        GLDS16(Ap1 + ko, &Asb[buf*4096 + wb + 2048]);
        GLDS16(Bp0 + ko, &Bsb[buf*4096 + wb]);
        GLDS16(Bp1 + ko, &Bsb[buf*4096 + wb + 2048]);
    };

    const int NT = 1024 / 32;
    stg(0, 0);
    int cur = 0;
    for (int kt = 0; kt < NT; ++kt) {
        __syncthreads();                       // drains stage of buf[cur]
        if (kt + 1 < NT) stg(cur ^ 1, kt + 1); // overlaps with compute below
        bf16x8 af[4], bf[4];
        #pragma unroll
        for (int f = 0; f < 4; ++f)
            af[f] = *reinterpret_cast<const bf16x8*>(
                reinterpret_cast<const char*>(&Asb[cur*4096 + (arow + f*16)*32]) + (kby ^ aswz));
        #pragma unroll
        for (int f = 0; f < 4; ++f)
            bf[f] = *reinterpret_cast<const bf16x8*>(
                reinterpret_cast<const char*>(&Bsb[cur*4096 + (brow + f*16)*32]) + (kby ^ bswz));
        #pragma unroll
        for (int i = 0; i < 4; ++i)
            #pragma unroll
            for (int j = 0; j < 4; ++j)
                acc[i][j] = __builtin_amdgcn_mfma_f32_16x16x32_bf16(af[i], bf[j], acc[i][j], 0, 0, 0);
        cur ^= 1;
    }

    // C-fragment layout: col = lane&15, row = (lane>>4)*4 + reg
    const int rbase = (lane >> 4) * 4;
    const int cbase = lane & 15;

    if (MODE == 0) {
        // ---- LDS-bounce epilogue: CT bf16 [128][128], chunk ^= row&7 ----
        __syncthreads();                       // K-loop LDS reads done everywhere
        const float qs = (z == 0) ? 0.125f : 1.0f;
        #pragma unroll
        for (int i = 0; i < 4; ++i)
            #pragma unroll
            for (int j = 0; j < 4; ++j)
                #pragma unroll
                for (int r = 0; r < 4; ++r) {
                    const int row = wm*64 + i*16 + rbase + r;
                    const int col = wn*64 + j*16 + cbase;
                    const int ch  = (col >> 3) ^ (row & 7);
                    reinterpret_cast<u16*>(reinterpret_cast<char*>(SH)
                        + row*256 + ch*16)[col & 7] = f2bf(acc[i][j][r] * qs);
                }
        __syncthreads();
        u16* dst = (z == 0) ? qh : (z == 1) ? kh : vh;
        const int li  = tid & 7;
        const int sg0 = tid >> 3;
        #pragma unroll
        for (int pass = 0; pass < 8; ++pass) {
            const int seg  = pass*32 + sg0;     // 0..255 = (row, half)
            const int row  = seg >> 1;
            const int half = seg & 1;
            const int ch   = (half*8 + li) ^ (row & 7);
            uint4 v = *reinterpret_cast<const uint4*>(
                reinterpret_cast<char*>(SH) + row*256 + ch*16);
            const int m = mBase + row;
            const int s = m >> 3, bb = m & 7;
            const int h = ((nBase + half*64) >> 6);
            *reinterpret_cast<uint4*>(dst + ((size_t)(bb*NH + h)*SEQ + s)*DH + li*8) = v;
        }
    } else {
        #pragma unroll
        for (int i = 0; i < 4; ++i)
            #pragma unroll
            for (int j = 0; j < 4; ++j)
                #pragma unroll
                for (int r = 0; r < 4; ++r) {
                    const int m = mBase + wm*64 + i*16 + rbase + r;
                    const int n = nBase + wn*64 + j*16 + cbase;
                    outp[(size_t)m*1024 + n] = acc[i][j][r] + bias[n];
                }
    }
}

// ------- transpose V + residual: vt[bh][d][s] = bf16(vh[bh][s][d] + x[s][b][h*64+d]) -------
__global__ __launch_bounds__(256) void vtrans_k(const u16* __restrict__ vh,
                                                const float* __restrict__ x,
                                                u16* __restrict__ vt) {
    __shared__ u16 T[64*64];
    const int tid = threadIdx.x;
    const int s0 = blockIdx.x * 64;
    const int bh = blockIdx.y;
    const int b  = bh >> 4;
    const int h  = bh & 15;
    const size_t base = (size_t)bh * (SEQ*DH);
    #pragma unroll
    for (int k = 0; k < 2; ++k) {
        const int idx = k*256 + tid;
        const int r = idx >> 3, c = idx & 7;
        union { uint4 v; u16 u[8]; } val;
        val.v = *reinterpret_cast<const uint4*>(vh + base + (size_t)(s0 + r)*DH + c*8);
        const float* xp = x + ((size_t)(s0 + r)*BSZ + b)*EMB + h*DH + c*8;
        float4 x0 = *reinterpret_cast<const float4*>(xp);
        float4 x1 = *reinterpret_cast<const float4*>(xp + 4);
        val.u[0]=f2bf(bf2f(val.u[0])+x0.x); val.u[1]=f2bf(bf2f(val.u[1])+x0.y);
        val.u[2]=f2bf(bf2f(val.u[2])+x0.z); val.u[3]=f2bf(bf2f(val.u[3])+x0.w);
        val.u[4]=f2bf(bf2f(val.u[4])+x1.x); val.u[5]=f2bf(bf2f(val.u[5])+x1.y);
        val.u[6]=f2bf(bf2f(val.u[6])+x1.z); val.u[7]=f2bf(bf2f(val.u[7])+x1.w);
        const int cs = c ^ (r & 7) ^ ((r >> 3) & 7);
        *reinterpret_cast<uint4*>(reinterpret_cast<char*>(T) + r*128 + cs*16) = val.v;
    }
    __syncthreads();
    #pragma unroll
    for (int k = 0; k < 2; ++k) {
        const int idx = k*256 + tid;
        const int d = idx >> 3, kc = idx & 7;
        union { u16 u[8]; uint4 v; } o;
        #pragma unroll
        for (int i = 0; i < 8; ++i) {
            const int s = kc*8 + i;
            const int ch = (d >> 3) ^ (s & 7) ^ ((s >> 3) & 7);
            o.u[i] = T[s*64 + ch*8 + (d & 7)];
        }
        *reinterpret_cast<uint4*>(vt + base + (size_t)d*SEQ + s0 + kc*8) = o.v;
    }
}

// ---------------- flash attention: LDS-staged K/V (GLDS16 + swizzle) ----------------
__global__ __launch_bounds__(256, 2) void attn_k(
    const u16* __restrict__ qh, const u16* __restrict__ kh,
    const u16* __restrict__ vt, const float* __restrict__ mask,
    u16* __restrict__ ctx)
{
    __shared__ u16 Kl[2][KVB*64];
    __shared__ u16 Vl[2][KVB*64];
    __shared__ u16 Pl[128*64];

    const int tid  = threadIdx.x;
    const int lane = tid & 63;
    const int wv   = tid >> 6;
    const int l15  = lane & 15;
    const int lg   = lane >> 4;

    const int d0 = blockIdx.y * 8 + blockIdx.x;
    const int bh = (d0 & 7) * 16 + (d0 >> 6);
    const int qt = (d0 >> 3) & 7;
    const int b  = bh >> 4;
    const int h  = bh & 15;
    const int qbase = qt * 128;
    const size_t bhOff = (size_t)bh * (SEQ*DH);

    const int rS = tid >> 3;
    const int cS = (tid & 7) ^ (rS & 7);
    const u16* kSrc = kh + bhOff + (size_t)rS*DH  + cS*8;
    const u16* vSrc = vt + bhOff + (size_t)rS*SEQ + cS*8;
    const int ldst = wv * 512;

    bf16x8 aq[2][2];
    #pragma unroll
    for (int fq = 0; fq < 2; ++fq)
        #pragma unroll
        for (int kk = 0; kk < 2; ++kk)
            aq[fq][kk] = *reinterpret_cast<const bf16x8*>(
                qh + bhOff + (size_t)(qbase + wv*32 + fq*16 + l15)*DH + kk*32 + lg*8);

    f32x4 o[2][4];
    float mrun[2][4], lrun[2][4];
    #pragma unroll
    for (int fq = 0; fq < 2; ++fq) {
        #pragma unroll
        for (int fd = 0; fd < 4; ++fd) o[fq][fd] = (f32x4){0.f,0.f,0.f,0.f};
        #pragma unroll
        for (int j = 0; j < 4; ++j) { mrun[fq][j] = -1e30f; lrun[fq][j] = 0.f; }
    }

    bf16x8 ones;
    #pragma unroll
    for (int i = 0; i < 8; ++i) ones[i] = (short)0x3F80;

    const int co0 = ((lg)     ^ (l15 & 7)) << 4;
    const int co1 = ((4 + lg) ^ (l15 & 7)) << 4;
    const float* mPtr = mask + (size_t)b*SEQ + l15;
    const int pq = wv*32;

    auto stage = [&](int buf, int kt) {
        const int jb = kt * KVB;
        GLDS16(kSrc + (size_t)jb*DH,        &Kl[buf][ldst]);
        GLDS16(kSrc + (size_t)(jb+32)*DH,   &Kl[buf][2048 + ldst]);
        GLDS16(vSrc + jb,                   &Vl[buf][ldst]);
        GLDS16(vSrc + 32*SEQ + jb,          &Vl[buf][2048 + ldst]);
    };

    stage(0, 0);
    int cur = 0;

    for (int kt = 0; kt < 16; ++kt) {
        __syncthreads();
        if (kt + 1 < 16) stage(cur ^ 1, kt + 1);
        const int jb = kt * KVB;

        f32x4 sc[2][4];
        const char* kb = reinterpret_cast<const char*>(&Kl[cur][0]) + l15*128;
        #pragma unroll
        for (int fn = 0; fn < 4; ++fn) {
            bf16x8 k0 = *reinterpret_cast<const bf16x8*>(kb + fn*2048 + co0);
            bf16x8 k1 = *reinterpret_cast<const bf16x8*>(kb + fn*2048 + co1);
            #pragma unroll
            for (int fq = 0; fq < 2; ++fq) {
                f32x4 t = __builtin_amdgcn_mfma_f32_16x16x32_bf16(aq[fq][0], k0,
                            (f32x4){0.f,0.f,0.f,0.f}, 0, 0, 0);
                sc[fq][fn] = __builtin_amdgcn_mfma_f32_16x16x32_bf16(aq[fq][1], k1, t, 0, 0, 0);
            }
        }
        float mv[4];
        #pragma unroll
        for (int fn = 0; fn < 4; ++fn) mv[fn] = mPtr[jb + fn*16];
        #pragma unroll
        for (int fq = 0; fq < 2; ++fq)
            #pragma unroll
            for (int fn = 0; fn < 4; ++fn)
                #pragma unroll
                for (int j = 0; j < 4; ++j) sc[fq][fn][j] += mv[fn];
        float mx[2][4];
        #pragma unroll
        for (int fq = 0; fq < 2; ++fq)
            #pragma unroll
            for (int j = 0; j < 4; ++j)
                mx[fq][j] = fmaxf(fmaxf(sc[fq][0][j], sc[fq][1][j]),
                                  fmaxf(sc[fq][2][j], sc[fq][3][j]));
        #pragma unroll
        for (int off = 1; off < 16; off <<= 1)
            #pragma unroll
            for (int fq = 0; fq < 2; ++fq)
                #pragma unroll
                for (int j = 0; j < 4; ++j)
                    mx[fq][j] = fmaxf(mx[fq][j], __shfl_xor(mx[fq][j], off));
        int need = 0;
        #pragma unroll
        for (int fq = 0; fq < 2; ++fq)
            #pragma unroll
            for (int j = 0; j < 4; ++j)
                need |= (mx[fq][j] > mrun[fq][j] + 8.0f);
        if (__any(need)) {
            #pragma unroll
            for (int fq = 0; fq < 2; ++fq)
                #pragma unroll
                for (int j = 0; j < 4; ++j) {
                    const float mn = fmaxf(mrun[fq][j], mx[fq][j]);
                    const float s  = __expf(mrun[fq][j] - mn);
                    mrun[fq][j] = mn;
                    lrun[fq][j] *= s;
                    #pragma unroll
                    for (int fd = 0; fd < 4; ++fd) o[fq][fd][j] *= s;
                }
        }
        #pragma unroll
        for (int fq = 0; fq < 2; ++fq)
            #pragma unroll
            for (int fn = 0; fn < 4; ++fn)
                #pragma unroll
                for (int j = 0; j < 4; ++j) {
                    const float p = __expf(sc[fq][fn][j] - mrun[fq][j]);
                    const int q = pq + fq*16 + lg*4 + j;
                    const int off = (q*128 + (fn*16 + l15)*2) ^ ((q & 7) << 4);
                    *reinterpret_cast<u16*>(reinterpret_cast<char*>(Pl) + off) =
                        (u16)(__float_as_uint(p) >> 16);
                }
        asm volatile("s_waitcnt lgkmcnt(0)" ::: "memory");
        __builtin_amdgcn_sched_barrier(0);
        bf16x8 pa[2][2];
        #pragma unroll
        for (int fq = 0; fq < 2; ++fq) {
            const int q = pq + fq*16 + l15;
            pa[fq][0] = *reinterpret_cast<const bf16x8*>(
                reinterpret_cast<char*>(Pl) + q*128 + co0);
            pa[fq][1] = *reinterpret_cast<const bf16x8*>(
                reinterpret_cast<char*>(Pl) + q*128 + co1);
        }
        #pragma unroll
        for (int fq = 0; fq < 2; ++fq) {
            f32x4 racc = __builtin_amdgcn_mfma_f32_16x16x32_bf16(pa[fq][0], ones,
                            (f32x4){0.f,0.f,0.f,0.f}, 0, 0, 0);
            racc = __builtin_amdgcn_mfma_f32_16x16x32_bf16(pa[fq][1], ones, racc, 0, 0, 0);
            #pragma unroll
            for (int j = 0; j < 4; ++j) lrun[fq][j] += racc[j];
        }
        const char* vb = reinterpret_cast<const char*>(&Vl[cur][0]) + l15*128;
        #pragma unroll
        for (int fd = 0; fd < 4; ++fd) {
            bf16x8 v0 = *reinterpret_cast<const bf16x8*>(vb + fd*2048 + co0);
            bf16x8 v1 = *reinterpret_cast<const bf16x8*>(vb + fd*2048 + co1);
            #pragma unroll
            for (int fq = 0; fq < 2; ++fq) {
                o[fq][fd] = __builtin_amdgcn_mfma_f32_16x16x32_bf16(pa[fq][0], v0, o[fq][fd], 0, 0, 0);
                o[fq][fd] = __builtin_amdgcn_mfma_f32_16x16x32_bf16(pa[fq][1], v1, o[fq][fd], 0, 0, 0);
            }
        }
        cur ^= 1;
    }

    #pragma unroll
    for (int fq = 0; fq < 2; ++fq)
        #pragma unroll
        for (int j = 0; j < 4; ++j) {
            const float inv = 1.0f / lrun[fq][j];
            const int s = qbase + wv*32 + fq*16 + lg*4 + j;
            #pragma unroll
            for (int fd = 0; fd < 4; ++fd) {
                const int d = fd*16 + l15;
                ctx[((size_t)(s*BSZ + b))*EMB + h*DH + d] = f2bf(o[fq][fd][j] * inv);
            }
        }
}

extern "C" void kernel_launch(void* const* d_in, const int* in_sizes, int n_in,
                              void* d_out, int out_size, void* d_ws, size_t ws_size,
                              hipStream_t stream) {
    const float* x    = (const float*)d_in[0];
    const float* mask = (const float*)d_in[1];
    const float* w_q  = (const float*)d_in[2];
    const float* w_k  = (const float*)d_in[3];
    const float* w_v  = (const float*)d_in[4];
    const float* w_o  = (const float*)d_in[5];
    const float* b_o  = (const float*)d_in[6];

    char* ws = (char*)d_ws;
    u16* xb  = (u16*)(ws);                        // 16 MB
    u16* wT  = (u16*)(ws + ((size_t)16 << 20));   // 8 MB
    u16* qh  = (u16*)(ws + ((size_t)24 << 20));   // 16 MB
    u16* kh  = (u16*)(ws + ((size_t)40 << 20));   // 16 MB
    u16* vt  = (u16*)(ws + ((size_t)56 << 20));   // 16 MB (V transposed)
    u16* vh  = (u16*)(ws + ((size_t)72 << 20));   // 16 MB
    u16* ctx = vh;                                // vh dead after vtrans
    float* outp = (float*)d_out;

    cvt_k<<<6144, 256, 0, stream>>>(x, w_q, w_k, w_v, w_o, xb, wT);
    gemm_bt<0><<<dim3(8, 64, 3), 256, 0, stream>>>(xb, wT, nullptr, qh, kh, vh, nullptr);
    vtrans_k<<<dim3(16, 128), 256, 0, stream>>>(vh, x, vt);
    attn_k<<<dim3(8, 128), 256, 0, stream>>>(qh, kh, vt, mask, ctx);
    gemm_bt<1><<<dim3(8, 64, 1), 256, 0, stream>>>(ctx, wT + (size_t)3*1048576, b_o,
                                                   nullptr, nullptr, nullptr, outp);
}

// Round 6
// 204.294 us; speedup vs baseline: 1.2930x; 1.0588x over previous
//
#include <hip/hip_runtime.h>

typedef unsigned short u16;
typedef unsigned int   u32;
typedef __attribute__((ext_vector_type(8))) short bf16x8;
typedef __attribute__((ext_vector_type(4))) short bf16x4;
typedef __attribute__((ext_vector_type(4))) float f32x4;

#define SEQ 1024
#define BSZ 8
#define EMB 1024
#define NH  16
#define DH  64
#define KVB 64
#define L2E 1.44269504088896f

__device__ __forceinline__ u16 f2bf(float f) {
    u32 u = __float_as_uint(f);
    u32 r = u + 0x7FFFu + ((u >> 16) & 1u);   // round-to-nearest-even
    return (u16)(r >> 16);
}
__device__ __forceinline__ float bf2f(u16 u) {
    return __uint_as_float((u32)u << 16);
}

#define GLDS16(g, l) __builtin_amdgcn_global_load_lds( \
    (const __attribute__((address_space(1))) void*)(g), \
    (__attribute__((address_space(3))) void*)(l), 16, 0, 0)

// ------- merged convert: x (fp32)->xb (bf16); w (K,N) fp32 -> wT (N,K) bf16 -------
__global__ __launch_bounds__(256) void cvt_k(
    const float* __restrict__ x, const float* __restrict__ w0,
    const float* __restrict__ w1, const float* __restrict__ w2,
    const float* __restrict__ w3, u16* __restrict__ xb, u16* __restrict__ wT)
{
    const int bid = blockIdx.x;
    if (bid < 4096) {
        size_t i = ((size_t)bid * 256 + threadIdx.x) * 8;
        float4 a = *reinterpret_cast<const float4*>(x + i);
        float4 b = *reinterpret_cast<const float4*>(x + i + 4);
        union { u16 u[8]; uint4 v; } o;
        o.u[0]=f2bf(a.x); o.u[1]=f2bf(a.y); o.u[2]=f2bf(a.z); o.u[3]=f2bf(a.w);
        o.u[4]=f2bf(b.x); o.u[5]=f2bf(b.y); o.u[6]=f2bf(b.z); o.u[7]=f2bf(b.w);
        *reinterpret_cast<uint4*>(xb + i) = o.v;
    } else {
        int id  = (bid - 4096) * 256 + threadIdx.x;
        int wi  = id >> 17;
        int rem = id & 131071;
        int kc  = rem >> 10;
        int n   = rem & 1023;
        const float* src = (wi==0) ? w0 : (wi==1) ? w1 : (wi==2) ? w2 : w3;
        union { u16 u[8]; uint4 v; } o;
        #pragma unroll
        for (int i = 0; i < 8; ++i) o.u[i] = f2bf(src[(size_t)(kc*8+i)*1024 + n]);
        *reinterpret_cast<uint4*>(wT + (size_t)wi*1048576 + (size_t)n*1024 + kc*8) = o.v;
    }
}

// ---------------- bf16 GEMM, C = A(M,K) * BT(N,K)^T ----------------
// m97 structure: 2 LDS buffers, __syncthreads, GLDS w=16 staging; conflict-free
// (r>>1)&3 chunk swizzle; XCD-bijective workgroup remap.
template<int MODE>
__global__ __launch_bounds__(256) void gemm_bt(
    const u16* __restrict__ A, const u16* __restrict__ BT,
    const float* __restrict__ bias,
    u16* __restrict__ qh, u16* __restrict__ kh, u16* __restrict__ vh,
    float* __restrict__ outp)
{
    __shared__ u16 SH[16384];            // 32KB: As 2x4096 | Bs 2x4096
    u16* Asb = SH;
    u16* Bsb = SH + 8192;

    const int tid  = threadIdx.x;
    const int lane = tid & 63;
    const int wv   = tid >> 6;
    const int wm   = wv >> 1, wn = wv & 1;

    const int nwg  = gridDim.x * gridDim.y * gridDim.z;
    const int flat = blockIdx.x + gridDim.x * (blockIdx.y + gridDim.y * blockIdx.z);
    const int rid  = (flat & 7) * (nwg >> 3) + (flat >> 3);
    const int nBlk = rid & 7;
    const int mBlk = (rid >> 3) & 63;
    const int z    = (MODE == 0) ? (rid >> 9) : 0;

    const int mBase = mBlk * 128;
    const int nBase = nBlk * 128;
    const u16* Bm = BT + (size_t)z * (1024*1024);

    const int r0  = tid >> 2;
    const int cb0 = (tid & 3) ^ ((r0 >> 1) & 3);
    const u16* Ap0 = A  + (size_t)(mBase + r0)      * 1024 + cb0*8;
    const u16* Ap1 = A  + (size_t)(mBase + r0 + 64) * 1024 + cb0*8;
    const u16* Bp0 = Bm + (size_t)(nBase + r0)      * 1024 + cb0*8;
    const u16* Bp1 = Bm + (size_t)(nBase + r0 + 64) * 1024 + cb0*8;
    const int wb = wv * 512;

    f32x4 acc[4][4];
    #pragma unroll
    for (int i = 0; i < 4; ++i)
        #pragma unroll
        for (int j = 0; j < 4; ++j) acc[i][j] = (f32x4){0.f,0.f,0.f,0.f};

    const int arow = wm*64 + (lane & 15);
    const int brow = wn*64 + (lane & 15);
    const int kby  = (lane >> 4) * 16;
    const int aswz = ((arow >> 1) & 3) << 4;
    const int bswz = ((brow >> 1) & 3) << 4;

    auto stg = [&](int buf, int kt) {
        const int ko = kt * 32;
        GLDS16(Ap0 + ko, &Asb[buf*4096 + wb]);
        GLDS16(Ap1 + ko, &Asb[buf*4096 + wb + 2048]);
        GLDS16(Bp0 + ko, &Bsb[buf*4096 + wb]);
        GLDS16(Bp1 + ko, &Bsb[buf*4096 + wb + 2048]);
    };

    const int NT = 1024 / 32;
    stg(0, 0);
    int cur = 0;
    for (int kt = 0; kt < NT; ++kt) {
        __syncthreads();
        if (kt + 1 < NT) stg(cur ^ 1, kt + 1);
        bf16x8 af[4], bf[4];
        #pragma unroll
        for (int f = 0; f < 4; ++f)
            af[f] = *reinterpret_cast<const bf16x8*>(
                reinterpret_cast<const char*>(&Asb[cur*4096 + (arow + f*16)*32]) + (kby ^ aswz));
        #pragma unroll
        for (int f = 0; f < 4; ++f)
            bf[f] = *reinterpret_cast<const bf16x8*>(
                reinterpret_cast<const char*>(&Bsb[cur*4096 + (brow + f*16)*32]) + (kby ^ bswz));
        #pragma unroll
        for (int i = 0; i < 4; ++i)
            #pragma unroll
            for (int j = 0; j < 4; ++j)
                acc[i][j] = __builtin_amdgcn_mfma_f32_16x16x32_bf16(af[i], bf[j], acc[i][j], 0, 0, 0);
        cur ^= 1;
    }

    const int rbase = (lane >> 4) * 4;
    const int cbase = lane & 15;

    if (MODE == 0) {
        // ---- LDS-bounce epilogue: CT bf16 [128][128], chunk ^= row&7 ----
        __syncthreads();
        // fold log2(e) into q so attention softmax can use exp2
        const float qs = (z == 0) ? 0.125f * L2E : 1.0f;
        #pragma unroll
        for (int i = 0; i < 4; ++i)
            #pragma unroll
            for (int j = 0; j < 4; ++j)
                #pragma unroll
                for (int r = 0; r < 4; ++r) {
                    const int row = wm*64 + i*16 + rbase + r;
                    const int col = wn*64 + j*16 + cbase;
                    const int ch  = (col >> 3) ^ (row & 7);
                    reinterpret_cast<u16*>(reinterpret_cast<char*>(SH)
                        + row*256 + ch*16)[col & 7] = f2bf(acc[i][j][r] * qs);
                }
        __syncthreads();
        u16* dst = (z == 0) ? qh : (z == 1) ? kh : vh;
        const int li  = tid & 7;
        const int sg0 = tid >> 3;
        #pragma unroll
        for (int pass = 0; pass < 8; ++pass) {
            const int seg  = pass*32 + sg0;
            const int row  = seg >> 1;
            const int half = seg & 1;
            const int ch   = (half*8 + li) ^ (row & 7);
            uint4 v = *reinterpret_cast<const uint4*>(
                reinterpret_cast<char*>(SH) + row*256 + ch*16);
            const int m = mBase + row;
            const int s = m >> 3, bb = m & 7;
            const int h = ((nBase + half*64) >> 6);
            *reinterpret_cast<uint4*>(dst + ((size_t)(bb*NH + h)*SEQ + s)*DH + li*8) = v;
        }
    } else {
        #pragma unroll
        for (int i = 0; i < 4; ++i)
            #pragma unroll
            for (int j = 0; j < 4; ++j)
                #pragma unroll
                for (int r = 0; r < 4; ++r) {
                    const int m = mBase + wm*64 + i*16 + rbase + r;
                    const int n = nBase + wn*64 + j*16 + cbase;
                    outp[(size_t)m*1024 + n] = acc[i][j][r] + bias[n];
                }
    }
}

// ------- transpose V + residual: vt[bh][d][s] = bf16(vh[bh][s][d] + x[s][b][h*64+d]) -------
__global__ __launch_bounds__(256) void vtrans_k(const u16* __restrict__ vh,
                                                const float* __restrict__ x,
                                                u16* __restrict__ vt) {
    __shared__ u16 T[64*64];
    const int tid = threadIdx.x;
    const int s0 = blockIdx.x * 64;
    const int bh = blockIdx.y;
    const int b  = bh >> 4;
    const int h  = bh & 15;
    const size_t base = (size_t)bh * (SEQ*DH);
    #pragma unroll
    for (int k = 0; k < 2; ++k) {
        const int idx = k*256 + tid;
        const int r = idx >> 3, c = idx & 7;
        union { uint4 v; u16 u[8]; } val;
        val.v = *reinterpret_cast<const uint4*>(vh + base + (size_t)(s0 + r)*DH + c*8);
        const float* xp = x + ((size_t)(s0 + r)*BSZ + b)*EMB + h*DH + c*8;
        float4 x0 = *reinterpret_cast<const float4*>(xp);
        float4 x1 = *reinterpret_cast<const float4*>(xp + 4);
        val.u[0]=f2bf(bf2f(val.u[0])+x0.x); val.u[1]=f2bf(bf2f(val.u[1])+x0.y);
        val.u[2]=f2bf(bf2f(val.u[2])+x0.z); val.u[3]=f2bf(bf2f(val.u[3])+x0.w);
        val.u[4]=f2bf(bf2f(val.u[4])+x1.x); val.u[5]=f2bf(bf2f(val.u[5])+x1.y);
        val.u[6]=f2bf(bf2f(val.u[6])+x1.z); val.u[7]=f2bf(bf2f(val.u[7])+x1.w);
        const int cs = c ^ (r & 7) ^ ((r >> 3) & 7);
        *reinterpret_cast<uint4*>(reinterpret_cast<char*>(T) + r*128 + cs*16) = val.v;
    }
    __syncthreads();
    #pragma unroll
    for (int k = 0; k < 2; ++k) {
        const int idx = k*256 + tid;
        const int d = idx >> 3, kc = idx & 7;
        union { u16 u[8]; uint4 v; } o;
        #pragma unroll
        for (int i = 0; i < 8; ++i) {
            const int s = kc*8 + i;
            const int ch = (d >> 3) ^ (s & 7) ^ ((s >> 3) & 7);
            o.u[i] = T[s*64 + ch*8 + (d & 7)];
        }
        *reinterpret_cast<uint4*>(vt + base + (size_t)d*SEQ + s0 + kc*8) = o.v;
    }
}

// ---------------- flash attention: swapped QK^T, in-register softmax ----------------
// ST = mfma(K, Q): lane owns full 16-key slices of ONE q-row (col=l15).
// PV uses k-slot permutation pi(lg,e)=4lg+(e&3)+16(e>>2) on BOTH P(A) and V(B):
// lane's own exp'd scores ARE its A-fragment (zero cross-lane movement, no P LDS).
__global__ __launch_bounds__(256, 4) void attn_k(
    const u16* __restrict__ qh, const u16* __restrict__ kh,
    const u16* __restrict__ vt, const float* __restrict__ mask,
    u16* __restrict__ ctx)
{
    __shared__ u16 Kl[2][KVB*64];   // [key][d], 16B chunks ^ (key&7)
    __shared__ u16 Vl[2][KVB*64];   // [d][key], 16B chunks ^ (d&7)

    const int tid  = threadIdx.x;
    const int lane = tid & 63;
    const int wv   = tid >> 6;
    const int l15  = lane & 15;
    const int lg   = lane >> 4;

    const int d0 = blockIdx.y * 8 + blockIdx.x;
    const int bh = (d0 & 7) * 16 + (d0 >> 6);
    const int qt = (d0 >> 3) & 7;
    const int b  = bh >> 4;
    const int h  = bh & 15;
    const int qbase = qt * 128;
    const size_t bhOff = (size_t)bh * (SEQ*DH);

    const int rS = tid >> 3;
    const int cS = (tid & 7) ^ (rS & 7);
    const u16* kSrc = kh + bhOff + (size_t)rS*DH  + cS*8;
    const u16* vSrc = vt + bhOff + (size_t)rS*SEQ + cS*8;
    const int ldst = wv * 512;

    // Q fragments (B-operand): col=q=l15, k(dh)=lg*8+e
    bf16x8 aq[2][2];
    #pragma unroll
    for (int fq = 0; fq < 2; ++fq)
        #pragma unroll
        for (int kk = 0; kk < 2; ++kk)
            aq[fq][kk] = *reinterpret_cast<const bf16x8*>(
                qh + bhOff + (size_t)(qbase + wv*32 + fq*16 + l15)*DH + kk*32 + lg*8);

    f32x4 o[2][4];
    float mrun[2], lrun[2];
    #pragma unroll
    for (int fq = 0; fq < 2; ++fq) {
        #pragma unroll
        for (int fd = 0; fd < 4; ++fd) o[fq][fd] = (f32x4){0.f,0.f,0.f,0.f};
        mrun[fq] = -1e30f; lrun[fq] = 0.f;
    }

    // K-fragment 16B chunk offsets (row=l15): chunk = (kk*4+lg) ^ (l15&7)
    const int co0 = ((lg)     ^ (l15 & 7)) << 4;
    const int co1 = ((4 + lg) ^ (l15 & 7)) << 4;
    // V b64 offsets per (kk,half): key = kk*32 + half*16 + 4*lg
    int voff[2][2];
    #pragma unroll
    for (int kk = 0; kk < 2; ++kk)
        #pragma unroll
        for (int hf = 0; hf < 2; ++hf)
            voff[kk][hf] = (((kk*4 + hf*2 + (lg >> 1)) ^ (l15 & 7)) << 4) + ((lg & 1) << 3);

    const float* mPtrT = mask + (size_t)b*SEQ + lg*4;

    auto stage = [&](int buf, int kt) {
        const int jb = kt * KVB;
        GLDS16(kSrc + (size_t)jb*DH,        &Kl[buf][ldst]);
        GLDS16(kSrc + (size_t)(jb+32)*DH,   &Kl[buf][2048 + ldst]);
        GLDS16(vSrc + jb,                   &Vl[buf][ldst]);
        GLDS16(vSrc + 32*SEQ + jb,          &Vl[buf][2048 + ldst]);
    };

    stage(0, 0);
    int cur = 0;

    for (int kt = 0; kt < 16; ++kt) {
        __syncthreads();
        if (kt + 1 < 16) stage(cur ^ 1, kt + 1);
        const int jb = kt * KVB;

        // ---- ST = K·Q^T: lane holds S[key=fn*16+lg*4+r][q=l15] ----
        f32x4 sc[2][4];
        const char* kb = reinterpret_cast<const char*>(&Kl[cur][0]) + l15*128;
        #pragma unroll
        for (int fn = 0; fn < 4; ++fn) {
            bf16x8 k0 = *reinterpret_cast<const bf16x8*>(kb + fn*2048 + co0);
            bf16x8 k1 = *reinterpret_cast<const bf16x8*>(kb + fn*2048 + co1);
            #pragma unroll
            for (int fq = 0; fq < 2; ++fq) {
                f32x4 t = __builtin_amdgcn_mfma_f32_16x16x32_bf16(k0, aq[fq][0],
                            (f32x4){0.f,0.f,0.f,0.f}, 0, 0, 0);
                sc[fq][fn] = __builtin_amdgcn_mfma_f32_16x16x32_bf16(k1, aq[fq][1], t, 0, 0, 0);
            }
        }
        // ---- mask (log2 domain): key = jb + fn*16 + lg*4 + r ----
        #pragma unroll
        for (int fn = 0; fn < 4; ++fn) {
            float4 mk = *reinterpret_cast<const float4*>(mPtrT + jb + fn*16);
            const float mkf[4] = {mk.x, mk.y, mk.z, mk.w};
            #pragma unroll
            for (int fq = 0; fq < 2; ++fq)
                #pragma unroll
                for (int r = 0; r < 4; ++r)
                    sc[fq][fn][r] = fmaf(mkf[r], L2E, sc[fq][fn][r]);
        }
        // ---- max: in-lane over 16, then lg-groups via 2 shfl ----
        float mx[2];
        #pragma unroll
        for (int fq = 0; fq < 2; ++fq) {
            float m01 = fmaxf(fmaxf(sc[fq][0][0], sc[fq][0][1]),
                              fmaxf(sc[fq][0][2], sc[fq][0][3]));
            #pragma unroll
            for (int fn = 1; fn < 4; ++fn)
                m01 = fmaxf(m01, fmaxf(fmaxf(sc[fq][fn][0], sc[fq][fn][1]),
                                       fmaxf(sc[fq][fn][2], sc[fq][fn][3])));
            m01 = fmaxf(m01, __shfl_xor(m01, 16));
            m01 = fmaxf(m01, __shfl_xor(m01, 32));
            mx[fq] = m01;
        }
        // ---- defer-max rescale (log2 domain, THR = 8*log2e) ----
        int need = (mx[0] > mrun[0] + 11.5f) | (mx[1] > mrun[1] + 11.5f);
        if (__any(need)) {
            #pragma unroll
            for (int fq = 0; fq < 2; ++fq) {
                const float mn  = fmaxf(mrun[fq], mx[fq]);
                const float scl = exp2f(mrun[fq] - mn);
                mrun[fq] = mn;
                lrun[fq] *= scl;
                float s4[4];
                #pragma unroll
                for (int r = 0; r < 4; ++r) s4[r] = __shfl(scl, lg*4 + r);
                #pragma unroll
                for (int fd = 0; fd < 4; ++fd)
                    #pragma unroll
                    for (int r = 0; r < 4; ++r) o[fq][fd][r] *= s4[r];
            }
        }
        // ---- P = exp2(sc - m), pack to bf16 pairs (A-frag under pi), row-sum ----
        u32 pw[2][2][4];   // [fq][kk][word]
        #pragma unroll
        for (int fq = 0; fq < 2; ++fq) {
            float rs = 0.f;
            #pragma unroll
            for (int fn = 0; fn < 4; ++fn) {
                const float p0 = exp2f(sc[fq][fn][0] - mrun[fq]);
                const float p1 = exp2f(sc[fq][fn][1] - mrun[fq]);
                const float p2 = exp2f(sc[fq][fn][2] - mrun[fq]);
                const float p3 = exp2f(sc[fq][fn][3] - mrun[fq]);
                rs += (p0 + p1) + (p2 + p3);
                u32 wA, wB;
                asm("v_cvt_pk_bf16_f32 %0, %1, %2" : "=v"(wA) : "v"(p0), "v"(p1));
                asm("v_cvt_pk_bf16_f32 %0, %1, %2" : "=v"(wB) : "v"(p2), "v"(p3));
                pw[fq][fn >> 1][(fn & 1)*2 + 0] = wA;
                pw[fq][fn >> 1][(fn & 1)*2 + 1] = wB;
            }
            rs += __shfl_xor(rs, 16);
            rs += __shfl_xor(rs, 32);
            lrun[fq] += rs;
        }
        // ---- O += P·V (k-slots permuted by pi on both operands) ----
        bf16x8 pa[2][2];
        #pragma unroll
        for (int fq = 0; fq < 2; ++fq)
            #pragma unroll
            for (int kk = 0; kk < 2; ++kk) {
                union { u32 w[4]; bf16x8 v; } u;
                u.w[0] = pw[fq][kk][0]; u.w[1] = pw[fq][kk][1];
                u.w[2] = pw[fq][kk][2]; u.w[3] = pw[fq][kk][3];
                pa[fq][kk] = u.v;
            }
        const char* vb = reinterpret_cast<const char*>(&Vl[cur][0]) + l15*128;
        #pragma unroll
        for (int fd = 0; fd < 4; ++fd) {
            #pragma unroll
            for (int kk = 0; kk < 2; ++kk) {
                union { bf16x4 h[2]; bf16x8 v; } vf;
                vf.h[0] = *reinterpret_cast<const bf16x4*>(vb + fd*2048 + voff[kk][0]);
                vf.h[1] = *reinterpret_cast<const bf16x4*>(vb + fd*2048 + voff[kk][1]);
                #pragma unroll
                for (int fq = 0; fq < 2; ++fq)
                    o[fq][fd] = __builtin_amdgcn_mfma_f32_16x16x32_bf16(pa[fq][kk], vf.v, o[fq][fd], 0, 0, 0);
            }
        }
        cur ^= 1;
    }

    // ---- epilogue: o[fq][fd][r] is (q=fq*16+lg*4+r, d=fd*16+l15); 1/l via shfl ----
    #pragma unroll
    for (int fq = 0; fq < 2; ++fq) {
        const float linv = 1.0f / lrun[fq];
        float inv4[4];
        #pragma unroll
        for (int r = 0; r < 4; ++r) inv4[r] = __shfl(linv, lg*4 + r);
        #pragma unroll
        for (int r = 0; r < 4; ++r) {
            const int s = qbase + wv*32 + fq*16 + lg*4 + r;
            #pragma unroll
            for (int fd = 0; fd < 4; ++fd) {
                const int d = fd*16 + l15;
                ctx[((size_t)(s*BSZ + b))*EMB + h*DH + d] = f2bf(o[fq][fd][r] * inv4[r]);
            }
        }
    }
}

extern "C" void kernel_launch(void* const* d_in, const int* in_sizes, int n_in,
                              void* d_out, int out_size, void* d_ws, size_t ws_size,
                              hipStream_t stream) {
    const float* x    = (const float*)d_in[0];
    const float* mask = (const float*)d_in[1];
    const float* w_q  = (const float*)d_in[2];
    const float* w_k  = (const float*)d_in[3];
    const float* w_v  = (const float*)d_in[4];
    const float* w_o  = (const float*)d_in[5];
    const float* b_o  = (const float*)d_in[6];

    char* ws = (char*)d_ws;
    u16* xb  = (u16*)(ws);                        // 16 MB
    u16* wT  = (u16*)(ws + ((size_t)16 << 20));   // 8 MB
    u16* qh  = (u16*)(ws + ((size_t)24 << 20));   // 16 MB
    u16* kh  = (u16*)(ws + ((size_t)40 << 20));   // 16 MB
    u16* vt  = (u16*)(ws + ((size_t)56 << 20));   // 16 MB (V transposed)
    u16* vh  = (u16*)(ws + ((size_t)72 << 20));   // 16 MB
    u16* ctx = vh;                                // vh dead after vtrans
    float* outp = (float*)d_out;

    cvt_k<<<6144, 256, 0, stream>>>(x, w_q, w_k, w_v, w_o, xb, wT);
    gemm_bt<0><<<dim3(8, 64, 3), 256, 0, stream>>>(xb, wT, nullptr, qh, kh, vh, nullptr);
    vtrans_k<<<dim3(16, 128), 256, 0, stream>>>(vh, x, vt);
    attn_k<<<dim3(8, 128), 256, 0, stream>>>(qh, kh, vt, mask, ctx);
    gemm_bt<1><<<dim3(8, 64, 1), 256, 0, stream>>>(ctx, wT + (size_t)3*1048576, b_o,
                                                   nullptr, nullptr, nullptr, outp);
}

// Round 7
// 200.376 us; speedup vs baseline: 1.3182x; 1.0196x over previous
//
#include <hip/hip_runtime.h>

typedef unsigned short u16;
typedef unsigned int   u32;
typedef __attribute__((ext_vector_type(8))) short bf16x8;
typedef __attribute__((ext_vector_type(4))) short bf16x4;
typedef __attribute__((ext_vector_type(4))) float f32x4;

#define SEQ 1024
#define BSZ 8
#define EMB 1024
#define NH  16
#define DH  64
#define KVB 64
#define L2E 1.44269504088896f

__device__ __forceinline__ u16 f2bf(float f) {
    u32 u = __float_as_uint(f);
    u32 r = u + 0x7FFFu + ((u >> 16) & 1u);   // round-to-nearest-even
    return (u16)(r >> 16);
}
__device__ __forceinline__ float bf2f(u16 u) {
    return __uint_as_float((u32)u << 16);
}

#define GLDS16(g, l) __builtin_amdgcn_global_load_lds( \
    (const __attribute__((address_space(1))) void*)(g), \
    (__attribute__((address_space(3))) void*)(l), 16, 0, 0)

// ------- merged convert: x (fp32)->xb (bf16); w (K,N) fp32 -> wT (N,K) bf16 -------
__global__ __launch_bounds__(256) void cvt_k(
    const float* __restrict__ x, const float* __restrict__ w0,
    const float* __restrict__ w1, const float* __restrict__ w2,
    const float* __restrict__ w3, u16* __restrict__ xb, u16* __restrict__ wT)
{
    const int bid = blockIdx.x;
    if (bid < 4096) {
        size_t i = ((size_t)bid * 256 + threadIdx.x) * 8;
        float4 a = *reinterpret_cast<const float4*>(x + i);
        float4 b = *reinterpret_cast<const float4*>(x + i + 4);
        union { u16 u[8]; uint4 v; } o;
        o.u[0]=f2bf(a.x); o.u[1]=f2bf(a.y); o.u[2]=f2bf(a.z); o.u[3]=f2bf(a.w);
        o.u[4]=f2bf(b.x); o.u[5]=f2bf(b.y); o.u[6]=f2bf(b.z); o.u[7]=f2bf(b.w);
        *reinterpret_cast<uint4*>(xb + i) = o.v;
    } else {
        int id  = (bid - 4096) * 256 + threadIdx.x;
        int wi  = id >> 17;
        int rem = id & 131071;
        int kc  = rem >> 10;
        int n   = rem & 1023;
        const float* src = (wi==0) ? w0 : (wi==1) ? w1 : (wi==2) ? w2 : w3;
        union { u16 u[8]; uint4 v; } o;
        #pragma unroll
        for (int i = 0; i < 8; ++i) o.u[i] = f2bf(src[(size_t)(kc*8+i)*1024 + n]);
        *reinterpret_cast<uint4*>(wT + (size_t)wi*1048576 + (size_t)n*1024 + kc*8) = o.v;
    }
}

// ---------------- proj GEMM: 8-wave counted-vmcnt pipeline ----------------
// C = A(8192,1024) * BT(3072,1024)^T. BM=256, BN=128, BK=32, 512 thr, 4 LDS bufs.
// Per iter: 8 ds_read_b128 | 3 GLDS (tile t+2) | vmcnt(3) | bar | lgkm0 | 16 MFMA | bar.
// Epilogue: LDS-bounce to head layout qh/kh/vh; q pre-scaled by 0.125*log2(e).
__global__ __launch_bounds__(512, 1) void gemm8_k(
    const u16* __restrict__ A, const u16* __restrict__ BT,
    u16* __restrict__ qh, u16* __restrict__ kh, u16* __restrict__ vh)
{
    __shared__ u16 As[4][256*32];   // 64KB
    __shared__ u16 Bs[4][128*32];   // 32KB

    const int tid  = threadIdx.x;
    const int lane = tid & 63;
    const int wv   = tid >> 6;      // 0..7
    const int wm   = wv >> 1;       // 0..3 (M)
    const int wn   = wv & 1;        // 0..1 (N)
    const int l15  = lane & 15;
    const int lg   = lane >> 4;

    // XCD-bijective remap (768 % 8 == 0); same-XCD WGs share an A panel
    const int flat = blockIdx.x;
    const int rid  = (flat & 7) * 96 + (flat >> 3);
    const int mBlk = rid / 24;
    const int nb   = rid - mBlk * 24;
    const int mBase = mBlk * 256;
    const int nBase = nb * 128;

    // staging: thread owns 16B chunk tid of each half (linear LDS dest);
    // global source chunk XOR-swizzled by (row>>1)&3 (read applies same XOR)
    const int rS = tid >> 2;                       // 0..127
    const int cS = (tid & 3) ^ ((rS >> 1) & 3);
    const u16* aSrc0 = A  + (size_t)(mBase + rS)       * 1024 + cS*8;
    const u16* aSrc1 = A  + (size_t)(mBase + 128 + rS) * 1024 + cS*8;  // same swz: (128+r)>>1&3 == (r>>1)&3
    const u16* bSrc  = BT + (size_t)(nBase + rS)       * 1024 + cS*8;
    const int wb = wv * 512;                       // u16: wave-uniform LDS base

    f32x4 acc[4][4];
    #pragma unroll
    for (int i = 0; i < 4; ++i)
        #pragma unroll
        for (int j = 0; j < 4; ++j) acc[i][j] = (f32x4){0.f,0.f,0.f,0.f};

    const int arow = wm*64 + l15;
    const int brow = wn*64 + l15;
    const int aoff = arow*64 + ((lg ^ ((arow >> 1) & 3)) << 4);  // bytes; +f*1024 per frag
    const int boff = brow*64 + ((lg ^ ((brow >> 1) & 3)) << 4);

    auto stg = [&](int buf, int kt) {
        const int ko = kt * 32;
        GLDS16(aSrc0 + ko, &As[buf][wb]);
        GLDS16(aSrc1 + ko, &As[buf][4096 + wb]);
        GLDS16(bSrc  + ko, &Bs[buf][wb]);
    };

    const int NT = 32;
    stg(0, 0);
    stg(1, 1);
    asm volatile("s_waitcnt vmcnt(3)" ::: "memory");   // tile 0 landed
    __builtin_amdgcn_s_barrier();

    for (int kt = 0; kt < NT; ++kt) {
        const int buf = kt & 3;
        bf16x8 af[4], bf[4];
        #pragma unroll
        for (int f = 0; f < 4; ++f)
            af[f] = *reinterpret_cast<const bf16x8*>(
                reinterpret_cast<const char*>(&As[buf][0]) + aoff + f*1024);
        #pragma unroll
        for (int j = 0; j < 4; ++j)
            bf[j] = *reinterpret_cast<const bf16x8*>(
                reinterpret_cast<const char*>(&Bs[buf][0]) + boff + j*1024);
        if (kt + 2 < NT) stg((kt + 2) & 3, kt + 2);
        if (kt + 2 < NT) {
            asm volatile("s_waitcnt vmcnt(3)" ::: "memory");  // tile kt+1 landed; kt+2 in flight
        } else {
            asm volatile("s_waitcnt vmcnt(0)" ::: "memory");  // drain tail
        }
        __builtin_amdgcn_s_barrier();
        asm volatile("s_waitcnt lgkmcnt(0)" ::: "memory");
        __builtin_amdgcn_sched_barrier(0);                    // rule 18
        __builtin_amdgcn_s_setprio(1);
        #pragma unroll
        for (int i = 0; i < 4; ++i)
            #pragma unroll
            for (int j = 0; j < 4; ++j)
                acc[i][j] = __builtin_amdgcn_mfma_f32_16x16x32_bf16(af[i], bf[j], acc[i][j], 0, 0, 0);
        __builtin_amdgcn_s_setprio(0);
        __builtin_amdgcn_s_barrier();
    }

    // ---- LDS-bounce epilogue: CT bf16 [256][128], chunk ^= row&7 ----
    const int z = nBase >> 10;                      // 0=q, 1=k, 2=v
    const float fac = (z == 0) ? 0.125f * L2E : 1.0f;
    u16* CT = &As[0][0];                            // 64KB, buffers dead
    const int rbase = (lane >> 4) * 4;
    #pragma unroll
    for (int i = 0; i < 4; ++i)
        #pragma unroll
        for (int j = 0; j < 4; ++j)
            #pragma unroll
            for (int r = 0; r < 4; ++r) {
                const int row = wm*64 + i*16 + rbase + r;
                const int col = wn*64 + j*16 + l15;
                const int ch  = (col >> 3) ^ (row & 7);
                reinterpret_cast<u16*>(reinterpret_cast<char*>(CT)
                    + row*256 + ch*16)[col & 7] = f2bf(acc[i][j][r] * fac);
            }
    __syncthreads();
    u16* dst = (z == 0) ? qh : (z == 1) ? kh : vh;
    #pragma unroll
    for (int p = 0; p < 8; ++p) {
        const int id  = p*512 + tid;
        const int row = id >> 4;
        const int c16 = id & 15;
        const int ch  = c16 ^ (row & 7);
        uint4 v = *reinterpret_cast<const uint4*>(
            reinterpret_cast<char*>(CT) + row*256 + ch*16);
        const int m  = mBase + row;
        const int s  = m >> 3, bb = m & 7;
        const int hc = nBase + c16*8;
        const int h  = (hc >> 6) & 15;
        *reinterpret_cast<uint4*>(dst + ((size_t)(bb*NH + h)*SEQ + s)*DH + (hc & 63)) = v;
    }
}

// ---------------- out-proj GEMM (128^2 m97 structure, proven) ----------------
__global__ __launch_bounds__(256) void gemm_o(
    const u16* __restrict__ A, const u16* __restrict__ BT,
    const float* __restrict__ bias, float* __restrict__ outp)
{
    __shared__ u16 SH[16384];
    u16* Asb = SH;
    u16* Bsb = SH + 8192;

    const int tid  = threadIdx.x;
    const int lane = tid & 63;
    const int wv   = tid >> 6;
    const int wm   = wv >> 1, wn = wv & 1;

    const int nwg  = gridDim.x * gridDim.y;
    const int flat = blockIdx.x + gridDim.x * blockIdx.y;
    const int rid  = (flat & 7) * (nwg >> 3) + (flat >> 3);
    const int nBlk = rid & 7;
    const int mBlk = (rid >> 3) & 63;

    const int mBase = mBlk * 128;
    const int nBase = nBlk * 128;

    const int r0  = tid >> 2;
    const int cb0 = (tid & 3) ^ ((r0 >> 1) & 3);
    const u16* Ap0 = A  + (size_t)(mBase + r0)      * 1024 + cb0*8;
    const u16* Ap1 = A  + (size_t)(mBase + r0 + 64) * 1024 + cb0*8;
    const u16* Bp0 = BT + (size_t)(nBase + r0)      * 1024 + cb0*8;
    const u16* Bp1 = BT + (size_t)(nBase + r0 + 64) * 1024 + cb0*8;
    const int wb = wv * 512;

    f32x4 acc[4][4];
    #pragma unroll
    for (int i = 0; i < 4; ++i)
        #pragma unroll
        for (int j = 0; j < 4; ++j) acc[i][j] = (f32x4){0.f,0.f,0.f,0.f};

    const int arow = wm*64 + (lane & 15);
    const int brow = wn*64 + (lane & 15);
    const int kby  = (lane >> 4) * 16;
    const int aswz = ((arow >> 1) & 3) << 4;
    const int bswz = ((brow >> 1) & 3) << 4;

    auto stg = [&](int buf, int kt) {
        const int ko = kt * 32;
        GLDS16(Ap0 + ko, &Asb[buf*4096 + wb]);
        GLDS16(Ap1 + ko, &Asb[buf*4096 + wb + 2048]);
        GLDS16(Bp0 + ko, &Bsb[buf*4096 + wb]);
        GLDS16(Bp1 + ko, &Bsb[buf*4096 + wb + 2048]);
    };

    const int NT = 1024 / 32;
    stg(0, 0);
    int cur = 0;
    for (int kt = 0; kt < NT; ++kt) {
        __syncthreads();
        if (kt + 1 < NT) stg(cur ^ 1, kt + 1);
        bf16x8 af[4], bf[4];
        #pragma unroll
        for (int f = 0; f < 4; ++f)
            af[f] = *reinterpret_cast<const bf16x8*>(
                reinterpret_cast<const char*>(&Asb[cur*4096 + (arow + f*16)*32]) + (kby ^ aswz));
        #pragma unroll
        for (int f = 0; f < 4; ++f)
            bf[f] = *reinterpret_cast<const bf16x8*>(
                reinterpret_cast<const char*>(&Bsb[cur*4096 + (brow + f*16)*32]) + (kby ^ bswz));
        #pragma unroll
        for (int i = 0; i < 4; ++i)
            #pragma unroll
            for (int j = 0; j < 4; ++j)
                acc[i][j] = __builtin_amdgcn_mfma_f32_16x16x32_bf16(af[i], bf[j], acc[i][j], 0, 0, 0);
        cur ^= 1;
    }

    const int rbase = (lane >> 4) * 4;
    const int cbase = lane & 15;
    #pragma unroll
    for (int i = 0; i < 4; ++i)
        #pragma unroll
        for (int j = 0; j < 4; ++j)
            #pragma unroll
            for (int r = 0; r < 4; ++r) {
                const int m = mBase + wm*64 + i*16 + rbase + r;
                const int n = nBase + wn*64 + j*16 + cbase;
                outp[(size_t)m*1024 + n] = acc[i][j][r] + bias[n];
            }
}

// ------- transpose V + residual: vt[bh][d][s] = bf16(vh[bh][s][d] + x[s][b][h*64+d]) -------
__global__ __launch_bounds__(256) void vtrans_k(const u16* __restrict__ vh,
                                                const float* __restrict__ x,
                                                u16* __restrict__ vt) {
    __shared__ u16 T[64*64];
    const int tid = threadIdx.x;
    const int s0 = blockIdx.x * 64;
    const int bh = blockIdx.y;
    const int b  = bh >> 4;
    const int h  = bh & 15;
    const size_t base = (size_t)bh * (SEQ*DH);
    #pragma unroll
    for (int k = 0; k < 2; ++k) {
        const int idx = k*256 + tid;
        const int r = idx >> 3, c = idx & 7;
        union { uint4 v; u16 u[8]; } val;
        val.v = *reinterpret_cast<const uint4*>(vh + base + (size_t)(s0 + r)*DH + c*8);
        const float* xp = x + ((size_t)(s0 + r)*BSZ + b)*EMB + h*DH + c*8;
        float4 x0 = *reinterpret_cast<const float4*>(xp);
        float4 x1 = *reinterpret_cast<const float4*>(xp + 4);
        val.u[0]=f2bf(bf2f(val.u[0])+x0.x); val.u[1]=f2bf(bf2f(val.u[1])+x0.y);
        val.u[2]=f2bf(bf2f(val.u[2])+x0.z); val.u[3]=f2bf(bf2f(val.u[3])+x0.w);
        val.u[4]=f2bf(bf2f(val.u[4])+x1.x); val.u[5]=f2bf(bf2f(val.u[5])+x1.y);
        val.u[6]=f2bf(bf2f(val.u[6])+x1.z); val.u[7]=f2bf(bf2f(val.u[7])+x1.w);
        const int cs = c ^ (r & 7) ^ ((r >> 3) & 7);
        *reinterpret_cast<uint4*>(reinterpret_cast<char*>(T) + r*128 + cs*16) = val.v;
    }
    __syncthreads();
    #pragma unroll
    for (int k = 0; k < 2; ++k) {
        const int idx = k*256 + tid;
        const int d = idx >> 3, kc = idx & 7;
        union { u16 u[8]; uint4 v; } o;
        #pragma unroll
        for (int i = 0; i < 8; ++i) {
            const int s = kc*8 + i;
            const int ch = (d >> 3) ^ (s & 7) ^ ((s >> 3) & 7);
            o.u[i] = T[s*64 + ch*8 + (d & 7)];
        }
        *reinterpret_cast<uint4*>(vt + base + (size_t)d*SEQ + s0 + kc*8) = o.v;
    }
}

// ---------------- flash attention: swapped QK^T, in-register softmax ----------------
__global__ __launch_bounds__(256, 4) void attn_k(
    const u16* __restrict__ qh, const u16* __restrict__ kh,
    const u16* __restrict__ vt, const float* __restrict__ mask,
    u16* __restrict__ ctx)
{
    __shared__ u16 Kl[2][KVB*64];   // [key][d], 16B chunks ^ (key&7)
    __shared__ u16 Vl[2][KVB*64];   // [d][key], 16B chunks ^ (d&7)

    const int tid  = threadIdx.x;
    const int lane = tid & 63;
    const int wv   = tid >> 6;
    const int l15  = lane & 15;
    const int lg   = lane >> 4;

    const int d0 = blockIdx.y * 8 + blockIdx.x;
    const int bh = (d0 & 7) * 16 + (d0 >> 6);
    const int qt = (d0 >> 3) & 7;
    const int b  = bh >> 4;
    const int h  = bh & 15;
    const int qbase = qt * 128;
    const size_t bhOff = (size_t)bh * (SEQ*DH);

    const int rS = tid >> 3;
    const int cS = (tid & 7) ^ (rS & 7);
    const u16* kSrc = kh + bhOff + (size_t)rS*DH  + cS*8;
    const u16* vSrc = vt + bhOff + (size_t)rS*SEQ + cS*8;
    const int ldst = wv * 512;

    bf16x8 aq[2][2];
    #pragma unroll
    for (int fq = 0; fq < 2; ++fq)
        #pragma unroll
        for (int kk = 0; kk < 2; ++kk)
            aq[fq][kk] = *reinterpret_cast<const bf16x8*>(
                qh + bhOff + (size_t)(qbase + wv*32 + fq*16 + l15)*DH + kk*32 + lg*8);

    f32x4 o[2][4];
    float mrun[2], lrun[2];
    #pragma unroll
    for (int fq = 0; fq < 2; ++fq) {
        #pragma unroll
        for (int fd = 0; fd < 4; ++fd) o[fq][fd] = (f32x4){0.f,0.f,0.f,0.f};
        mrun[fq] = -1e30f; lrun[fq] = 0.f;
    }

    const int co0 = ((lg)     ^ (l15 & 7)) << 4;
    const int co1 = ((4 + lg) ^ (l15 & 7)) << 4;
    int voff[2][2];
    #pragma unroll
    for (int kk = 0; kk < 2; ++kk)
        #pragma unroll
        for (int hf = 0; hf < 2; ++hf)
            voff[kk][hf] = (((kk*4 + hf*2 + (lg >> 1)) ^ (l15 & 7)) << 4) + ((lg & 1) << 3);

    const float* mPtrT = mask + (size_t)b*SEQ + lg*4;

    auto stage = [&](int buf, int kt) {
        const int jb = kt * KVB;
        GLDS16(kSrc + (size_t)jb*DH,        &Kl[buf][ldst]);
        GLDS16(kSrc + (size_t)(jb+32)*DH,   &Kl[buf][2048 + ldst]);
        GLDS16(vSrc + jb,                   &Vl[buf][ldst]);
        GLDS16(vSrc + 32*SEQ + jb,          &Vl[buf][2048 + ldst]);
    };

    stage(0, 0);
    int cur = 0;

    for (int kt = 0; kt < 16; ++kt) {
        __syncthreads();
        if (kt + 1 < 16) stage(cur ^ 1, kt + 1);
        const int jb = kt * KVB;

        f32x4 sc[2][4];
        const char* kb = reinterpret_cast<const char*>(&Kl[cur][0]) + l15*128;
        #pragma unroll
        for (int fn = 0; fn < 4; ++fn) {
            bf16x8 k0 = *reinterpret_cast<const bf16x8*>(kb + fn*2048 + co0);
            bf16x8 k1 = *reinterpret_cast<const bf16x8*>(kb + fn*2048 + co1);
            #pragma unroll
            for (int fq = 0; fq < 2; ++fq) {
                f32x4 t = __builtin_amdgcn_mfma_f32_16x16x32_bf16(k0, aq[fq][0],
                            (f32x4){0.f,0.f,0.f,0.f}, 0, 0, 0);
                sc[fq][fn] = __builtin_amdgcn_mfma_f32_16x16x32_bf16(k1, aq[fq][1], t, 0, 0, 0);
            }
        }
        #pragma unroll
        for (int fn = 0; fn < 4; ++fn) {
            float4 mk = *reinterpret_cast<const float4*>(mPtrT + jb + fn*16);
            const float mkf[4] = {mk.x, mk.y, mk.z, mk.w};
            #pragma unroll
            for (int fq = 0; fq < 2; ++fq)
                #pragma unroll
                for (int r = 0; r < 4; ++r)
                    sc[fq][fn][r] = fmaf(mkf[r], L2E, sc[fq][fn][r]);
        }
        float mx[2];
        #pragma unroll
        for (int fq = 0; fq < 2; ++fq) {
            float m01 = fmaxf(fmaxf(sc[fq][0][0], sc[fq][0][1]),
                              fmaxf(sc[fq][0][2], sc[fq][0][3]));
            #pragma unroll
            for (int fn = 1; fn < 4; ++fn)
                m01 = fmaxf(m01, fmaxf(fmaxf(sc[fq][fn][0], sc[fq][fn][1]),
                                       fmaxf(sc[fq][fn][2], sc[fq][fn][3])));
            m01 = fmaxf(m01, __shfl_xor(m01, 16));
            m01 = fmaxf(m01, __shfl_xor(m01, 32));
            mx[fq] = m01;
        }
        int need = (mx[0] > mrun[0] + 11.5f) | (mx[1] > mrun[1] + 11.5f);
        if (__any(need)) {
            #pragma unroll
            for (int fq = 0; fq < 2; ++fq) {
                const float mn  = fmaxf(mrun[fq], mx[fq]);
                const float scl = exp2f(mrun[fq] - mn);
                mrun[fq] = mn;
                lrun[fq] *= scl;
                float s4[4];
                #pragma unroll
                for (int r = 0; r < 4; ++r) s4[r] = __shfl(scl, lg*4 + r);
                #pragma unroll
                for (int fd = 0; fd < 4; ++fd)
                    #pragma unroll
                    for (int r = 0; r < 4; ++r) o[fq][fd][r] *= s4[r];
            }
        }
        u32 pw[2][2][4];
        #pragma unroll
        for (int fq = 0; fq < 2; ++fq) {
            float rs = 0.f;
            #pragma unroll
            for (int fn = 0; fn < 4; ++fn) {
                const float p0 = exp2f(sc[fq][fn][0] - mrun[fq]);
                const float p1 = exp2f(sc[fq][fn][1] - mrun[fq]);
                const float p2 = exp2f(sc[fq][fn][2] - mrun[fq]);
                const float p3 = exp2f(sc[fq][fn][3] - mrun[fq]);
                rs += (p0 + p1) + (p2 + p3);
                u32 wA, wB;
                asm("v_cvt_pk_bf16_f32 %0, %1, %2" : "=v"(wA) : "v"(p0), "v"(p1));
                asm("v_cvt_pk_bf16_f32 %0, %1, %2" : "=v"(wB) : "v"(p2), "v"(p3));
                pw[fq][fn >> 1][(fn & 1)*2 + 0] = wA;
                pw[fq][fn >> 1][(fn & 1)*2 + 1] = wB;
            }
            rs += __shfl_xor(rs, 16);
            rs += __shfl_xor(rs, 32);
            lrun[fq] += rs;
        }
        bf16x8 pa[2][2];
        #pragma unroll
        for (int fq = 0; fq < 2; ++fq)
            #pragma unroll
            for (int kk = 0; kk < 2; ++kk) {
                union { u32 w[4]; bf16x8 v; } u;
                u.w[0] = pw[fq][kk][0]; u.w[1] = pw[fq][kk][1];
                u.w[2] = pw[fq][kk][2]; u.w[3] = pw[fq][kk][3];
                pa[fq][kk] = u.v;
            }
        const char* vb = reinterpret_cast<const char*>(&Vl[cur][0]) + l15*128;
        #pragma unroll
        for (int fd = 0; fd < 4; ++fd) {
            #pragma unroll
            for (int kk = 0; kk < 2; ++kk) {
                union { bf16x4 h[2]; bf16x8 v; } vf;
                vf.h[0] = *reinterpret_cast<const bf16x4*>(vb + fd*2048 + voff[kk][0]);
                vf.h[1] = *reinterpret_cast<const bf16x4*>(vb + fd*2048 + voff[kk][1]);
                #pragma unroll
                for (int fq = 0; fq < 2; ++fq)
                    o[fq][fd] = __builtin_amdgcn_mfma_f32_16x16x32_bf16(pa[fq][kk], vf.v, o[fq][fd], 0, 0, 0);
            }
        }
        cur ^= 1;
    }

    #pragma unroll
    for (int fq = 0; fq < 2; ++fq) {
        const float linv = 1.0f / lrun[fq];
        float inv4[4];
        #pragma unroll
        for (int r = 0; r < 4; ++r) inv4[r] = __shfl(linv, lg*4 + r);
        #pragma unroll
        for (int r = 0; r < 4; ++r) {
            const int s = qbase + wv*32 + fq*16 + lg*4 + r;
            #pragma unroll
            for (int fd = 0; fd < 4; ++fd) {
                const int d = fd*16 + l15;
                ctx[((size_t)(s*BSZ + b))*EMB + h*DH + d] = f2bf(o[fq][fd][r] * inv4[r]);
            }
        }
    }
}

extern "C" void kernel_launch(void* const* d_in, const int* in_sizes, int n_in,
                              void* d_out, int out_size, void* d_ws, size_t ws_size,
                              hipStream_t stream) {
    const float* x    = (const float*)d_in[0];
    const float* mask = (const float*)d_in[1];
    const float* w_q  = (const float*)d_in[2];
    const float* w_k  = (const float*)d_in[3];
    const float* w_v  = (const float*)d_in[4];
    const float* w_o  = (const float*)d_in[5];
    const float* b_o  = (const float*)d_in[6];

    char* ws = (char*)d_ws;
    u16* xb  = (u16*)(ws);                        // 16 MB
    u16* wT  = (u16*)(ws + ((size_t)16 << 20));   // 8 MB
    u16* qh  = (u16*)(ws + ((size_t)24 << 20));   // 16 MB
    u16* kh  = (u16*)(ws + ((size_t)40 << 20));   // 16 MB
    u16* vt  = (u16*)(ws + ((size_t)56 << 20));   // 16 MB (V transposed)
    u16* vh  = (u16*)(ws + ((size_t)72 << 20));   // 16 MB
    u16* ctx = vh;                                // vh dead after vtrans
    float* outp = (float*)d_out;

    cvt_k<<<6144, 256, 0, stream>>>(x, w_q, w_k, w_v, w_o, xb, wT);
    gemm8_k<<<768, 512, 0, stream>>>(xb, wT, qh, kh, vh);
    vtrans_k<<<dim3(16, 128), 256, 0, stream>>>(vh, x, vt);
    attn_k<<<dim3(8, 128), 256, 0, stream>>>(qh, kh, vt, mask, ctx);
    gemm_o<<<dim3(8, 64), 256, 0, stream>>>(ctx, wT + (size_t)3*1048576, b_o, outp);
}

// Round 8
// 185.701 us; speedup vs baseline: 1.4224x; 1.0790x over previous
//
#include <hip/hip_runtime.h>

typedef unsigned short u16;
typedef unsigned int   u32;
typedef __attribute__((ext_vector_type(8))) short bf16x8;
typedef __attribute__((ext_vector_type(4))) float f32x4;

#define SEQ 1024
#define BSZ 8
#define EMB 1024
#define NH  16
#define DH  64
#define KVB 64
#define L2E 1.44269504088896f

__device__ __forceinline__ u16 f2bf(float f) {
    u32 u = __float_as_uint(f);
    u32 r = u + 0x7FFFu + ((u >> 16) & 1u);   // round-to-nearest-even
    return (u16)(r >> 16);
}
__device__ __forceinline__ float bf2f(u16 u) {
    return __uint_as_float((u32)u << 16);
}
__device__ __forceinline__ float fexp2(float x) {
    return __builtin_amdgcn_exp2f(x);         // bare v_exp_f32 (libm exp2f has fixup bloat)
}

#define GLDS16(g, l) __builtin_amdgcn_global_load_lds( \
    (const __attribute__((address_space(1))) void*)(g), \
    (__attribute__((address_space(3))) void*)(l), 16, 0, 0)

// ------- merged convert: x (fp32)->xb (bf16); w (K,N) fp32 -> wT (N,K) bf16 -------
__global__ __launch_bounds__(256) void cvt_k(
    const float* __restrict__ x, const float* __restrict__ w0,
    const float* __restrict__ w1, const float* __restrict__ w2,
    const float* __restrict__ w3, u16* __restrict__ xb, u16* __restrict__ wT)
{
    const int bid = blockIdx.x;
    if (bid < 4096) {
        size_t i = ((size_t)bid * 256 + threadIdx.x) * 8;
        float4 a = *reinterpret_cast<const float4*>(x + i);
        float4 b = *reinterpret_cast<const float4*>(x + i + 4);
        union { u16 u[8]; uint4 v; } o;
        o.u[0]=f2bf(a.x); o.u[1]=f2bf(a.y); o.u[2]=f2bf(a.z); o.u[3]=f2bf(a.w);
        o.u[4]=f2bf(b.x); o.u[5]=f2bf(b.y); o.u[6]=f2bf(b.z); o.u[7]=f2bf(b.w);
        *reinterpret_cast<uint4*>(xb + i) = o.v;
    } else {
        int id  = (bid - 4096) * 256 + threadIdx.x;
        int wi  = id >> 17;
        int rem = id & 131071;
        int kc  = rem >> 10;
        int n   = rem & 1023;
        const float* src = (wi==0) ? w0 : (wi==1) ? w1 : (wi==2) ? w2 : w3;
        union { u16 u[8]; uint4 v; } o;
        #pragma unroll
        for (int i = 0; i < 8; ++i) o.u[i] = f2bf(src[(size_t)(kc*8+i)*1024 + n]);
        *reinterpret_cast<uint4*>(wT + (size_t)wi*1048576 + (size_t)n*1024 + kc*8) = o.v;
    }
}

// ---------------- proj GEMM: 8-wave, 3-deep counted-vmcnt pipeline ----------------
// BM=256, BN=128, BK=32, 512 thr, 4 LDS bufs, ONE barrier/iter.
// Steady state: wait vmcnt(6) -> barrier -> ds_read(kt) | stg(kt+3) -> lgkm0 -> 16 MFMA.
__global__ __launch_bounds__(512, 1) void gemm8_k(
    const u16* __restrict__ A, const u16* __restrict__ BT,
    u16* __restrict__ qh, u16* __restrict__ kh, u16* __restrict__ vh)
{
    __shared__ u16 As[4][256*32];   // 64KB
    __shared__ u16 Bs[4][128*32];   // 32KB

    const int tid  = threadIdx.x;
    const int lane = tid & 63;
    const int wv   = tid >> 6;
    const int wm   = wv >> 1;
    const int wn   = wv & 1;
    const int l15  = lane & 15;
    const int lg   = lane >> 4;

    const int flat = blockIdx.x;
    const int rid  = (flat & 7) * 96 + (flat >> 3);
    const int mBlk = rid / 24;
    const int nb   = rid - mBlk * 24;
    const int mBase = mBlk * 256;
    const int nBase = nb * 128;

    const int rS = tid >> 2;
    const int cS = (tid & 3) ^ ((rS >> 1) & 3);
    const u16* aSrc0 = A  + (size_t)(mBase + rS)       * 1024 + cS*8;
    const u16* aSrc1 = A  + (size_t)(mBase + 128 + rS) * 1024 + cS*8;
    const u16* bSrc  = BT + (size_t)(nBase + rS)       * 1024 + cS*8;
    const int wb = wv * 512;

    f32x4 acc[4][4];
    #pragma unroll
    for (int i = 0; i < 4; ++i)
        #pragma unroll
        for (int j = 0; j < 4; ++j) acc[i][j] = (f32x4){0.f,0.f,0.f,0.f};

    const int arow = wm*64 + l15;
    const int brow = wn*64 + l15;
    const int aoff = arow*64 + ((lg ^ ((arow >> 1) & 3)) << 4);
    const int boff = brow*64 + ((lg ^ ((brow >> 1) & 3)) << 4);

    auto stg = [&](int buf, int kt) {
        const int ko = kt * 32;
        GLDS16(aSrc0 + ko, &As[buf][wb]);
        GLDS16(aSrc1 + ko, &As[buf][4096 + wb]);
        GLDS16(bSrc  + ko, &Bs[buf][wb]);
    };

    const int NT = 32;
    stg(0, 0);
    stg(1, 1);
    stg(2, 2);

    for (int kt = 0; kt < NT; ++kt) {
        if (kt < NT - 2)       asm volatile("s_waitcnt vmcnt(6)" ::: "memory");
        else if (kt == NT - 2) asm volatile("s_waitcnt vmcnt(3)" ::: "memory");
        else                   asm volatile("s_waitcnt vmcnt(0)" ::: "memory");
        __builtin_amdgcn_s_barrier();
        const int buf = kt & 3;
        bf16x8 af[4], bf4[4];
        #pragma unroll
        for (int f = 0; f < 4; ++f)
            af[f] = *reinterpret_cast<const bf16x8*>(
                reinterpret_cast<const char*>(&As[buf][0]) + aoff + f*1024);
        #pragma unroll
        for (int j = 0; j < 4; ++j)
            bf4[j] = *reinterpret_cast<const bf16x8*>(
                reinterpret_cast<const char*>(&Bs[buf][0]) + boff + j*1024);
        if (kt + 3 < NT) stg((kt + 3) & 3, kt + 3);
        asm volatile("s_waitcnt lgkmcnt(0)" ::: "memory");
        __builtin_amdgcn_sched_barrier(0);
        __builtin_amdgcn_s_setprio(1);
        #pragma unroll
        for (int i = 0; i < 4; ++i)
            #pragma unroll
            for (int j = 0; j < 4; ++j)
                acc[i][j] = __builtin_amdgcn_mfma_f32_16x16x32_bf16(af[i], bf4[j], acc[i][j], 0, 0, 0);
        __builtin_amdgcn_s_setprio(0);
    }

    // ---- LDS-bounce epilogue: CT bf16 [256][128], chunk ^= row&7 ----
    __syncthreads();                                // all tile reads done
    const int z = nBase >> 10;
    const float fac = (z == 0) ? 0.125f * L2E : 1.0f;
    u16* CT = &As[0][0];
    const int rbase = (lane >> 4) * 4;
    #pragma unroll
    for (int i = 0; i < 4; ++i)
        #pragma unroll
        for (int j = 0; j < 4; ++j)
            #pragma unroll
            for (int r = 0; r < 4; ++r) {
                const int row = wm*64 + i*16 + rbase + r;
                const int col = wn*64 + j*16 + l15;
                const int ch  = (col >> 3) ^ (row & 7);
                reinterpret_cast<u16*>(reinterpret_cast<char*>(CT)
                    + row*256 + ch*16)[col & 7] = f2bf(acc[i][j][r] * fac);
            }
    __syncthreads();
    u16* dst = (z == 0) ? qh : (z == 1) ? kh : vh;
    #pragma unroll
    for (int p = 0; p < 8; ++p) {
        const int id  = p*512 + tid;
        const int row = id >> 4;
        const int c16 = id & 15;
        const int ch  = c16 ^ (row & 7);
        uint4 v = *reinterpret_cast<const uint4*>(
            reinterpret_cast<char*>(CT) + row*256 + ch*16);
        const int m  = mBase + row;
        const int s  = m >> 3, bb = m & 7;
        const int hc = nBase + c16*8;
        const int h  = (hc >> 6) & 15;
        *reinterpret_cast<uint4*>(dst + ((size_t)(bb*NH + h)*SEQ + s)*DH + (hc & 63)) = v;
    }
}

// ---------------- out-proj GEMM (128^2 m97 structure, proven) ----------------
__global__ __launch_bounds__(256) void gemm_o(
    const u16* __restrict__ A, const u16* __restrict__ BT,
    const float* __restrict__ bias, float* __restrict__ outp)
{
    __shared__ u16 SH[16384];
    u16* Asb = SH;
    u16* Bsb = SH + 8192;

    const int tid  = threadIdx.x;
    const int lane = tid & 63;
    const int wv   = tid >> 6;
    const int wm   = wv >> 1, wn = wv & 1;

    const int nwg  = gridDim.x * gridDim.y;
    const int flat = blockIdx.x + gridDim.x * blockIdx.y;
    const int rid  = (flat & 7) * (nwg >> 3) + (flat >> 3);
    const int nBlk = rid & 7;
    const int mBlk = (rid >> 3) & 63;

    const int mBase = mBlk * 128;
    const int nBase = nBlk * 128;

    const int r0  = tid >> 2;
    const int cb0 = (tid & 3) ^ ((r0 >> 1) & 3);
    const u16* Ap0 = A  + (size_t)(mBase + r0)      * 1024 + cb0*8;
    const u16* Ap1 = A  + (size_t)(mBase + r0 + 64) * 1024 + cb0*8;
    const u16* Bp0 = BT + (size_t)(nBase + r0)      * 1024 + cb0*8;
    const u16* Bp1 = BT + (size_t)(nBase + r0 + 64) * 1024 + cb0*8;
    const int wb = wv * 512;

    f32x4 acc[4][4];
    #pragma unroll
    for (int i = 0; i < 4; ++i)
        #pragma unroll
        for (int j = 0; j < 4; ++j) acc[i][j] = (f32x4){0.f,0.f,0.f,0.f};

    const int arow = wm*64 + (lane & 15);
    const int brow = wn*64 + (lane & 15);
    const int kby  = (lane >> 4) * 16;
    const int aswz = ((arow >> 1) & 3) << 4;
    const int bswz = ((brow >> 1) & 3) << 4;

    auto stg = [&](int buf, int kt) {
        const int ko = kt * 32;
        GLDS16(Ap0 + ko, &Asb[buf*4096 + wb]);
        GLDS16(Ap1 + ko, &Asb[buf*4096 + wb + 2048]);
        GLDS16(Bp0 + ko, &Bsb[buf*4096 + wb]);
        GLDS16(Bp1 + ko, &Bsb[buf*4096 + wb + 2048]);
    };

    const int NT = 1024 / 32;
    stg(0, 0);
    int cur = 0;
    for (int kt = 0; kt < NT; ++kt) {
        __syncthreads();
        if (kt + 1 < NT) stg(cur ^ 1, kt + 1);
        bf16x8 af[4], bf4[4];
        #pragma unroll
        for (int f = 0; f < 4; ++f)
            af[f] = *reinterpret_cast<const bf16x8*>(
                reinterpret_cast<const char*>(&Asb[cur*4096 + (arow + f*16)*32]) + (kby ^ aswz));
        #pragma unroll
        for (int f = 0; f < 4; ++f)
            bf4[f] = *reinterpret_cast<const bf16x8*>(
                reinterpret_cast<const char*>(&Bsb[cur*4096 + (brow + f*16)*32]) + (kby ^ bswz));
        #pragma unroll
        for (int i = 0; i < 4; ++i)
            #pragma unroll
            for (int j = 0; j < 4; ++j)
                acc[i][j] = __builtin_amdgcn_mfma_f32_16x16x32_bf16(af[i], bf4[j], acc[i][j], 0, 0, 0);
        cur ^= 1;
    }

    const int rbase = (lane >> 4) * 4;
    const int cbase = lane & 15;
    #pragma unroll
    for (int i = 0; i < 4; ++i)
        #pragma unroll
        for (int j = 0; j < 4; ++j)
            #pragma unroll
            for (int r = 0; r < 4; ++r) {
                const int m = mBase + wm*64 + i*16 + rbase + r;
                const int n = nBase + wn*64 + j*16 + cbase;
                outp[(size_t)m*1024 + n] = acc[i][j][r] + bias[n];
            }
}

// ------- transpose V + residual, KEY-PERMUTED for b128 PV reads --------
// vt[bh][d][s0 + 32*(s>>5) + pos(s&31)], pos(s)= (s&3) + 4*((s>>4)&1) + 8*((s>>2)&3)
// so that PV B-slot (lg,e) [key = 16(e>>2)+4lg+(e&3)] is contiguous at pos 8lg+e.
__global__ __launch_bounds__(256) void vtrans_k(const u16* __restrict__ vh,
                                                const float* __restrict__ x,
                                                u16* __restrict__ vt) {
    __shared__ u16 T[64*64];
    const int tid = threadIdx.x;
    const int s0 = blockIdx.x * 64;
    const int bh = blockIdx.y;
    const int b  = bh >> 4;
    const int h  = bh & 15;
    const size_t base = (size_t)bh * (SEQ*DH);
    #pragma unroll
    for (int k = 0; k < 2; ++k) {
        const int idx = k*256 + tid;
        const int r = idx >> 3, c = idx & 7;
        union { uint4 v; u16 u[8]; } val;
        val.v = *reinterpret_cast<const uint4*>(vh + base + (size_t)(s0 + r)*DH + c*8);
        const float* xp = x + ((size_t)(s0 + r)*BSZ + b)*EMB + h*DH + c*8;
        float4 x0 = *reinterpret_cast<const float4*>(xp);
        float4 x1 = *reinterpret_cast<const float4*>(xp + 4);
        val.u[0]=f2bf(bf2f(val.u[0])+x0.x); val.u[1]=f2bf(bf2f(val.u[1])+x0.y);
        val.u[2]=f2bf(bf2f(val.u[2])+x0.z); val.u[3]=f2bf(bf2f(val.u[3])+x0.w);
        val.u[4]=f2bf(bf2f(val.u[4])+x1.x); val.u[5]=f2bf(bf2f(val.u[5])+x1.y);
        val.u[6]=f2bf(bf2f(val.u[6])+x1.z); val.u[7]=f2bf(bf2f(val.u[7])+x1.w);
        const int cs = c ^ (r & 7) ^ ((r >> 3) & 7);
        *reinterpret_cast<uint4*>(reinterpret_cast<char*>(T) + r*128 + cs*16) = val.v;
    }
    __syncthreads();
    #pragma unroll
    for (int k = 0; k < 2; ++k) {
        const int idx = k*256 + tid;
        const int d = idx >> 3, kc = idx & 7;
        union { u16 u[8]; uint2 w[2]; } o;
        #pragma unroll
        for (int i = 0; i < 8; ++i) {
            const int s = kc*8 + i;
            const int ch = (d >> 3) ^ (s & 7) ^ ((s >> 3) & 7);
            o.u[i] = T[s*64 + ch*8 + (d & 7)];
        }
        // permuted store: s = kc*8 + i -> pos
        const int blk = (kc >> 2) * 32;
        const int hbit = (kc >> 1) & 1;
        const int g20 = (2*kc) & 3;
        const int g21 = (2*kc + 1) & 3;
        u16* basep = vt + base + (size_t)d*SEQ + s0 + blk + 4*hbit;
        *reinterpret_cast<uint2*>(basep + 8*g20) = o.w[0];   // i=0..3
        *reinterpret_cast<uint2*>(basep + 8*g21) = o.w[1];   // i=4..7
    }
}

// ---------------- flash attention: swapped QK^T, in-register softmax ----------------
// ST = mfma(K, Q): lane owns 16-key slices of ONE q-row. PV uses k-slot perm
// pi(lg,e)=16(e>>2)+4lg+(e&3) on both P (in-lane pack order) and V (pre-permuted
// in vt by vtrans_k) -> V fragments are single b128 reads at the K-read offsets.
__global__ __launch_bounds__(256, 4) void attn_k(
    const u16* __restrict__ qh, const u16* __restrict__ kh,
    const u16* __restrict__ vt, const float* __restrict__ mask,
    u16* __restrict__ ctx)
{
    __shared__ u16 Kl[2][KVB*64];   // [key][d], 16B chunks ^ (key&7)
    __shared__ u16 Vl[2][KVB*64];   // [d][permuted key], 16B chunks ^ (d&7)

    const int tid  = threadIdx.x;
    const int lane = tid & 63;
    const int wv   = tid >> 6;
    const int l15  = lane & 15;
    const int lg   = lane >> 4;

    const int d0 = blockIdx.y * 8 + blockIdx.x;
    const int bh = (d0 & 7) * 16 + (d0 >> 6);
    const int qt = (d0 >> 3) & 7;
    const int b  = bh >> 4;
    const int h  = bh & 15;
    const int qbase = qt * 128;
    const size_t bhOff = (size_t)bh * (SEQ*DH);

    const int rS = tid >> 3;
    const int cS = (tid & 7) ^ (rS & 7);
    const u16* kSrc = kh + bhOff + (size_t)rS*DH  + cS*8;
    const u16* vSrc = vt + bhOff + (size_t)rS*SEQ + cS*8;
    const int ldst = wv * 512;

    bf16x8 aq[2][2];
    #pragma unroll
    for (int fq = 0; fq < 2; ++fq)
        #pragma unroll
        for (int kk = 0; kk < 2; ++kk)
            aq[fq][kk] = *reinterpret_cast<const bf16x8*>(
                qh + bhOff + (size_t)(qbase + wv*32 + fq*16 + l15)*DH + kk*32 + lg*8);

    f32x4 o[2][4];
    float mrun[2], lrun[2];
    #pragma unroll
    for (int fq = 0; fq < 2; ++fq) {
        #pragma unroll
        for (int fd = 0; fd < 4; ++fd) o[fq][fd] = (f32x4){0.f,0.f,0.f,0.f};
        mrun[fq] = -1e30f; lrun[fq] = 0.f;
    }

    const int co0 = ((lg)     ^ (l15 & 7)) << 4;
    const int co1 = ((4 + lg) ^ (l15 & 7)) << 4;
    const float* mPtrT = mask + (size_t)b*SEQ + lg*4;

    auto stage = [&](int buf, int kt) {
        const int jb = kt * KVB;
        GLDS16(kSrc + (size_t)jb*DH,        &Kl[buf][ldst]);
        GLDS16(kSrc + (size_t)(jb+32)*DH,   &Kl[buf][2048 + ldst]);
        GLDS16(vSrc + jb,                   &Vl[buf][ldst]);
        GLDS16(vSrc + 32*SEQ + jb,          &Vl[buf][2048 + ldst]);
    };

    stage(0, 0);
    int cur = 0;

    for (int kt = 0; kt < 16; ++kt) {
        __syncthreads();
        if (kt + 1 < 16) stage(cur ^ 1, kt + 1);
        const int jb = kt * KVB;

        // ---- ST = K·Q^T ----
        f32x4 sc[2][4];
        const char* kb = reinterpret_cast<const char*>(&Kl[cur][0]) + l15*128;
        #pragma unroll
        for (int fn = 0; fn < 4; ++fn) {
            bf16x8 k0 = *reinterpret_cast<const bf16x8*>(kb + fn*2048 + co0);
            bf16x8 k1 = *reinterpret_cast<const bf16x8*>(kb + fn*2048 + co1);
            #pragma unroll
            for (int fq = 0; fq < 2; ++fq) {
                f32x4 t = __builtin_amdgcn_mfma_f32_16x16x32_bf16(k0, aq[fq][0],
                            (f32x4){0.f,0.f,0.f,0.f}, 0, 0, 0);
                sc[fq][fn] = __builtin_amdgcn_mfma_f32_16x16x32_bf16(k1, aq[fq][1], t, 0, 0, 0);
            }
        }
        // ---- mask (log2 domain) ----
        #pragma unroll
        for (int fn = 0; fn < 4; ++fn) {
            float4 mk = *reinterpret_cast<const float4*>(mPtrT + jb + fn*16);
            const float mkf[4] = {mk.x, mk.y, mk.z, mk.w};
            #pragma unroll
            for (int fq = 0; fq < 2; ++fq)
                #pragma unroll
                for (int r = 0; r < 4; ++r)
                    sc[fq][fn][r] = fmaf(mkf[r], L2E, sc[fq][fn][r]);
        }
        // ---- max ----
        float mx[2];
        #pragma unroll
        for (int fq = 0; fq < 2; ++fq) {
            float m01 = fmaxf(fmaxf(sc[fq][0][0], sc[fq][0][1]),
                              fmaxf(sc[fq][0][2], sc[fq][0][3]));
            #pragma unroll
            for (int fn = 1; fn < 4; ++fn)
                m01 = fmaxf(m01, fmaxf(fmaxf(sc[fq][fn][0], sc[fq][fn][1]),
                                       fmaxf(sc[fq][fn][2], sc[fq][fn][3])));
            m01 = fmaxf(m01, __shfl_xor(m01, 16));
            m01 = fmaxf(m01, __shfl_xor(m01, 32));
            mx[fq] = m01;
        }
        // ---- defer-max rescale ----
        int need = (mx[0] > mrun[0] + 11.5f) | (mx[1] > mrun[1] + 11.5f);
        if (__any(need)) {
            #pragma unroll
            for (int fq = 0; fq < 2; ++fq) {
                const float mn  = fmaxf(mrun[fq], mx[fq]);
                const float scl = fexp2(mrun[fq] - mn);
                mrun[fq] = mn;
                lrun[fq] *= scl;
                float s4[4];
                #pragma unroll
                for (int r = 0; r < 4; ++r) s4[r] = __shfl(scl, lg*4 + r);
                #pragma unroll
                for (int fd = 0; fd < 4; ++fd)
                    #pragma unroll
                    for (int r = 0; r < 4; ++r) o[fq][fd][r] *= s4[r];
            }
        }
        // ---- P = exp2(sc - m), pack (A-frag under pi), row-sum ----
        u32 pw[2][2][4];
        #pragma unroll
        for (int fq = 0; fq < 2; ++fq) {
            float rs = 0.f;
            #pragma unroll
            for (int fn = 0; fn < 4; ++fn) {
                const float p0 = fexp2(sc[fq][fn][0] - mrun[fq]);
                const float p1 = fexp2(sc[fq][fn][1] - mrun[fq]);
                const float p2 = fexp2(sc[fq][fn][2] - mrun[fq]);
                const float p3 = fexp2(sc[fq][fn][3] - mrun[fq]);
                rs += (p0 + p1) + (p2 + p3);
                u32 wA, wB;
                asm("v_cvt_pk_bf16_f32 %0, %1, %2" : "=v"(wA) : "v"(p0), "v"(p1));
                asm("v_cvt_pk_bf16_f32 %0, %1, %2" : "=v"(wB) : "v"(p2), "v"(p3));
                pw[fq][fn >> 1][(fn & 1)*2 + 0] = wA;
                pw[fq][fn >> 1][(fn & 1)*2 + 1] = wB;
            }
            rs += __shfl_xor(rs, 16);
            rs += __shfl_xor(rs, 32);
            lrun[fq] += rs;
        }
        bf16x8 pa[2][2];
        #pragma unroll
        for (int fq = 0; fq < 2; ++fq)
            #pragma unroll
            for (int kk = 0; kk < 2; ++kk) {
                union { u32 w[4]; bf16x8 v; } u;
                u.w[0] = pw[fq][kk][0]; u.w[1] = pw[fq][kk][1];
                u.w[2] = pw[fq][kk][2]; u.w[3] = pw[fq][kk][3];
                pa[fq][kk] = u.v;
            }
        // ---- O += P·V : V pre-permuted -> b128 reads at K-read offsets ----
        const char* vb = reinterpret_cast<const char*>(&Vl[cur][0]) + l15*128;
        #pragma unroll
        for (int kk = 0; kk < 2; ++kk) {
            const int coff = kk ? co1 : co0;
            #pragma unroll
            for (int fd = 0; fd < 4; ++fd) {
                bf16x8 vf = *reinterpret_cast<const bf16x8*>(vb + fd*2048 + coff);
                #pragma unroll
                for (int fq = 0; fq < 2; ++fq)
                    o[fq][fd] = __builtin_amdgcn_mfma_f32_16x16x32_bf16(pa[fq][kk], vf, o[fq][fd], 0, 0, 0);
            }
        }
        cur ^= 1;
    }

    #pragma unroll
    for (int fq = 0; fq < 2; ++fq) {
        const float linv = 1.0f / lrun[fq];
        float inv4[4];
        #pragma unroll
        for (int r = 0; r < 4; ++r) inv4[r] = __shfl(linv, lg*4 + r);
        #pragma unroll
        for (int r = 0; r < 4; ++r) {
            const int s = qbase + wv*32 + fq*16 + lg*4 + r;
            #pragma unroll
            for (int fd = 0; fd < 4; ++fd) {
                const int d = fd*16 + l15;
                ctx[((size_t)(s*BSZ + b))*EMB + h*DH + d] = f2bf(o[fq][fd][r] * inv4[r]);
            }
        }
    }
}

extern "C" void kernel_launch(void* const* d_in, const int* in_sizes, int n_in,
                              void* d_out, int out_size, void* d_ws, size_t ws_size,
                              hipStream_t stream) {
    const float* x    = (const float*)d_in[0];
    const float* mask = (const float*)d_in[1];
    const float* w_q  = (const float*)d_in[2];
    const float* w_k  = (const float*)d_in[3];
    const float* w_v  = (const float*)d_in[4];
    const float* w_o  = (const float*)d_in[5];
    const float* b_o  = (const float*)d_in[6];

    char* ws = (char*)d_ws;
    u16* xb  = (u16*)(ws);                        // 16 MB
    u16* wT  = (u16*)(ws + ((size_t)16 << 20));   // 8 MB
    u16* qh  = (u16*)(ws + ((size_t)24 << 20));   // 16 MB
    u16* kh  = (u16*)(ws + ((size_t)40 << 20));   // 16 MB
    u16* vt  = (u16*)(ws + ((size_t)56 << 20));   // 16 MB (V transposed + key-permuted)
    u16* vh  = (u16*)(ws + ((size_t)72 << 20));   // 16 MB
    u16* ctx = vh;                                // vh dead after vtrans
    float* outp = (float*)d_out;

    cvt_k<<<6144, 256, 0, stream>>>(x, w_q, w_k, w_v, w_o, xb, wT);
    gemm8_k<<<768, 512, 0, stream>>>(xb, wT, qh, kh, vh);
    vtrans_k<<<dim3(16, 128), 256, 0, stream>>>(vh, x, vt);
    attn_k<<<dim3(8, 128), 256, 0, stream>>>(qh, kh, vt, mask, ctx);
    gemm_o<<<dim3(8, 64), 256, 0, stream>>>(ctx, wT + (size_t)3*1048576, b_o, outp);
}

// Round 9
// 176.090 us; speedup vs baseline: 1.5001x; 1.0546x over previous
//
#include <hip/hip_runtime.h>

typedef unsigned short u16;
typedef unsigned int   u32;
typedef __attribute__((ext_vector_type(8))) short bf16x8;
typedef __attribute__((ext_vector_type(4))) float f32x4;

#define SEQ 1024
#define BSZ 8
#define EMB 1024
#define NH  16
#define DH  64
#define KVB 64
#define L2E 1.44269504088896f

__device__ __forceinline__ u16 f2bf(float f) {
    u32 u = __float_as_uint(f);
    u32 r = u + 0x7FFFu + ((u >> 16) & 1u);   // round-to-nearest-even
    return (u16)(r >> 16);
}
__device__ __forceinline__ float bf2f(u16 u) {
    return __uint_as_float((u32)u << 16);
}
__device__ __forceinline__ float fexp2(float x) {
    return __builtin_amdgcn_exp2f(x);
}

#define GLDS16(g, l) __builtin_amdgcn_global_load_lds( \
    (const __attribute__((address_space(1))) void*)(g), \
    (__attribute__((address_space(3))) void*)(l), 16, 0, 0)

// ------- merged convert: x (fp32)->xb (bf16); w (K,N) fp32 -> wT (N,K) bf16 -------
__global__ __launch_bounds__(256) void cvt_k(
    const float* __restrict__ x, const float* __restrict__ w0,
    const float* __restrict__ w1, const float* __restrict__ w2,
    const float* __restrict__ w3, u16* __restrict__ xb, u16* __restrict__ wT)
{
    const int bid = blockIdx.x;
    if (bid < 4096) {
        size_t i = ((size_t)bid * 256 + threadIdx.x) * 8;
        float4 a = *reinterpret_cast<const float4*>(x + i);
        float4 b = *reinterpret_cast<const float4*>(x + i + 4);
        union { u16 u[8]; uint4 v; } o;
        o.u[0]=f2bf(a.x); o.u[1]=f2bf(a.y); o.u[2]=f2bf(a.z); o.u[3]=f2bf(a.w);
        o.u[4]=f2bf(b.x); o.u[5]=f2bf(b.y); o.u[6]=f2bf(b.z); o.u[7]=f2bf(b.w);
        *reinterpret_cast<uint4*>(xb + i) = o.v;
    } else {
        int id  = (bid - 4096) * 256 + threadIdx.x;
        int wi  = id >> 17;
        int rem = id & 131071;
        int kc  = rem >> 10;
        int n   = rem & 1023;
        const float* src = (wi==0) ? w0 : (wi==1) ? w1 : (wi==2) ? w2 : w3;
        union { u16 u[8]; uint4 v; } o;
        #pragma unroll
        for (int i = 0; i < 8; ++i) o.u[i] = f2bf(src[(size_t)(kc*8+i)*1024 + n]);
        *reinterpret_cast<uint4*>(wT + (size_t)wi*1048576 + (size_t)n*1024 + kc*8) = o.v;
    }
}

// ---------------- GEMM: BM=128 x BN=256, 4 waves (2Mx2N), wave=64x128 ----------------
// 3 LDS buffers (72KB) -> 2 WGs/CU; counted vmcnt(6), 1 barrier/iter.
// MODE 0: proj, BT has 3072 rows (q|k|v); LDS-bounce head-layout epilogue.
// MODE 1: out-proj, fp32 + bias epilogue.
template<int MODE>
__global__ __launch_bounds__(256, 2) void gemm_t(
    const u16* __restrict__ A, const u16* __restrict__ BT,
    const float* __restrict__ bias,
    u16* __restrict__ qh, u16* __restrict__ kh, u16* __restrict__ vh,
    float* __restrict__ outp)
{
    __shared__ u16 SH[36864];                 // 72KB
    u16* Asb = SH;                            // 3 x 4096 u16 (128x32)
    u16* Bsb = SH + 12288;                    // 3 x 8192 u16 (256x32)

    const int tid  = threadIdx.x;
    const int lane = tid & 63;
    const int wv   = tid >> 6;                // 0..3
    const int wm   = wv >> 1;                 // M half
    const int wn   = wv & 1;                  // N half
    const int l15  = lane & 15;
    const int lg   = lane >> 4;

    // XCD-bijective remap (nwg % 8 == 0)
    const int nwg  = gridDim.x;
    const int flat = blockIdx.x;
    const int rid  = (flat & 7) * (nwg >> 3) + (flat >> 3);
    const int NB   = (MODE == 0) ? 12 : 4;    // N blocks of 256
    const int mBlk = rid / NB;
    const int nb   = rid - mBlk * NB;
    const int mBase = mBlk * 128;
    const int nBase = nb * 256;

    // staging: 256 threads x 16B = 4KB per GLDS; source chunk swizzled by (row>>1)&3
    const int rS = tid >> 2;                  // 0..63
    const int cS = (tid & 3) ^ ((rS >> 1) & 3);
    const u16* aSrc = A  + (size_t)(mBase + rS) * 1024 + cS*8;
    const u16* bSrc = BT + (size_t)(nBase + rS) * 1024 + cS*8;
    const int wb = wv * 512;                  // wave segment (u16) within 4KB chunk

    f32x4 acc[4][8];
    #pragma unroll
    for (int i = 0; i < 4; ++i)
        #pragma unroll
        for (int j = 0; j < 8; ++j) acc[i][j] = (f32x4){0.f,0.f,0.f,0.f};

    const int arow = wm*64  + l15;
    const int brow = wn*128 + l15;
    const int aoff = arow*64 + ((lg ^ ((arow >> 1) & 3)) << 4);  // +i*1024 per frag
    const int boff = brow*64 + ((lg ^ ((brow >> 1) & 3)) << 4);  // +j*1024 per frag

    auto stg = [&](int buf, int kt) {
        const int ko = kt * 32;
        GLDS16(aSrc + ko,                    &Asb[buf*4096 + wb]);
        GLDS16(aSrc + (size_t)64*1024 + ko,  &Asb[buf*4096 + 2048 + wb]);
        GLDS16(bSrc + ko,                    &Bsb[buf*8192 + wb]);
        GLDS16(bSrc + (size_t)64*1024 + ko,  &Bsb[buf*8192 + 2048 + wb]);
        GLDS16(bSrc + (size_t)128*1024 + ko, &Bsb[buf*8192 + 4096 + wb]);
        GLDS16(bSrc + (size_t)192*1024 + ko, &Bsb[buf*8192 + 6144 + wb]);
    };

    const int NT = 32;
    stg(0, 0);
    stg(1, 1);
    int cur = 0, nxt = 2;
    for (int kt = 0; kt < NT; ++kt) {
        if (kt < NT - 1) asm volatile("s_waitcnt vmcnt(6)" ::: "memory");
        else             asm volatile("s_waitcnt vmcnt(0)" ::: "memory");
        __builtin_amdgcn_s_barrier();
        bf16x8 af[4], bf[8];
        #pragma unroll
        for (int i = 0; i < 4; ++i)
            af[i] = *reinterpret_cast<const bf16x8*>(
                reinterpret_cast<const char*>(&Asb[cur*4096]) + aoff + i*1024);
        #pragma unroll
        for (int j = 0; j < 8; ++j)
            bf[j] = *reinterpret_cast<const bf16x8*>(
                reinterpret_cast<const char*>(&Bsb[cur*8192]) + boff + j*1024);
        if (kt + 2 < NT) stg(nxt, kt + 2);
        asm volatile("s_waitcnt lgkmcnt(0)" ::: "memory");
        __builtin_amdgcn_sched_barrier(0);
        __builtin_amdgcn_s_setprio(1);
        #pragma unroll
        for (int i = 0; i < 4; ++i)
            #pragma unroll
            for (int j = 0; j < 8; ++j)
                acc[i][j] = __builtin_amdgcn_mfma_f32_16x16x32_bf16(af[i], bf[j], acc[i][j], 0, 0, 0);
        __builtin_amdgcn_s_setprio(0);
        cur = (cur == 2) ? 0 : cur + 1;
        nxt = (nxt == 2) ? 0 : nxt + 1;
    }

    const int rbase = lg * 4;

    if (MODE == 0) {
        // ---- LDS-bounce: CT bf16 [128][256], 16B chunk ^= row&7 (64KB of SH) ----
        __syncthreads();
        const int z = nBase >> 10;            // nb/4: 0=q, 1=k, 2=v
        const float fac = (z == 0) ? 0.125f * L2E : 1.0f;
        #pragma unroll
        for (int i = 0; i < 4; ++i)
            #pragma unroll
            for (int j = 0; j < 8; ++j)
                #pragma unroll
                for (int r = 0; r < 4; ++r) {
                    const int row = wm*64 + i*16 + rbase + r;
                    const int col = wn*128 + j*16 + l15;
                    const int ch  = (col >> 3) ^ (row & 7);
                    reinterpret_cast<u16*>(reinterpret_cast<char*>(SH)
                        + row*512 + ch*16)[col & 7] = f2bf(acc[i][j][r] * fac);
                }
        __syncthreads();
        u16* dst = (z == 0) ? qh : (z == 1) ? kh : vh;
        #pragma unroll
        for (int p = 0; p < 16; ++p) {
            const int id  = p*256 + tid;
            const int row = id >> 5;
            const int c16 = id & 31;
            const int ch  = c16 ^ (row & 7);
            uint4 v = *reinterpret_cast<const uint4*>(
                reinterpret_cast<char*>(SH) + row*512 + ch*16);
            const int m = mBase + row;
            const int s = m >> 3, bb = m & 7;
            const int n = nBase + c16*8;
            const int h = (n >> 6) & 15;
            *reinterpret_cast<uint4*>(dst + ((size_t)(bb*NH + h)*SEQ + s)*DH + (n & 63)) = v;
        }
    } else {
        #pragma unroll
        for (int i = 0; i < 4; ++i)
            #pragma unroll
            for (int j = 0; j < 8; ++j)
                #pragma unroll
                for (int r = 0; r < 4; ++r) {
                    const int m = mBase + wm*64 + i*16 + rbase + r;
                    const int n = nBase + wn*128 + j*16 + l15;
                    outp[(size_t)m*1024 + n] = acc[i][j][r] + bias[n];
                }
    }
}

// ------- transpose V + residual, KEY-PERMUTED for b128 PV reads --------
__global__ __launch_bounds__(256) void vtrans_k(const u16* __restrict__ vh,
                                                const float* __restrict__ x,
                                                u16* __restrict__ vt) {
    __shared__ u16 T[64*64];
    const int tid = threadIdx.x;
    const int s0 = blockIdx.x * 64;
    const int bh = blockIdx.y;
    const int b  = bh >> 4;
    const int h  = bh & 15;
    const size_t base = (size_t)bh * (SEQ*DH);
    #pragma unroll
    for (int k = 0; k < 2; ++k) {
        const int idx = k*256 + tid;
        const int r = idx >> 3, c = idx & 7;
        union { uint4 v; u16 u[8]; } val;
        val.v = *reinterpret_cast<const uint4*>(vh + base + (size_t)(s0 + r)*DH + c*8);
        const float* xp = x + ((size_t)(s0 + r)*BSZ + b)*EMB + h*DH + c*8;
        float4 x0 = *reinterpret_cast<const float4*>(xp);
        float4 x1 = *reinterpret_cast<const float4*>(xp + 4);
        val.u[0]=f2bf(bf2f(val.u[0])+x0.x); val.u[1]=f2bf(bf2f(val.u[1])+x0.y);
        val.u[2]=f2bf(bf2f(val.u[2])+x0.z); val.u[3]=f2bf(bf2f(val.u[3])+x0.w);
        val.u[4]=f2bf(bf2f(val.u[4])+x1.x); val.u[5]=f2bf(bf2f(val.u[5])+x1.y);
        val.u[6]=f2bf(bf2f(val.u[6])+x1.z); val.u[7]=f2bf(bf2f(val.u[7])+x1.w);
        const int cs = c ^ (r & 7) ^ ((r >> 3) & 7);
        *reinterpret_cast<uint4*>(reinterpret_cast<char*>(T) + r*128 + cs*16) = val.v;
    }
    __syncthreads();
    #pragma unroll
    for (int k = 0; k < 2; ++k) {
        const int idx = k*256 + tid;
        const int d = idx >> 3, kc = idx & 7;
        union { u16 u[8]; uint2 w[2]; } o;
        #pragma unroll
        for (int i = 0; i < 8; ++i) {
            const int s = kc*8 + i;
            const int ch = (d >> 3) ^ (s & 7) ^ ((s >> 3) & 7);
            o.u[i] = T[s*64 + ch*8 + (d & 7)];
        }
        const int blk = (kc >> 2) * 32;
        const int hbit = (kc >> 1) & 1;
        const int g20 = (2*kc) & 3;
        const int g21 = (2*kc + 1) & 3;
        u16* basep = vt + base + (size_t)d*SEQ + s0 + blk + 4*hbit;
        *reinterpret_cast<uint2*>(basep + 8*g20) = o.w[0];
        *reinterpret_cast<uint2*>(basep + 8*g21) = o.w[1];
    }
}

// ---------------- flash attention: swapped QK^T, in-register softmax ----------------
__global__ __launch_bounds__(256, 4) void attn_k(
    const u16* __restrict__ qh, const u16* __restrict__ kh,
    const u16* __restrict__ vt, const float* __restrict__ mask,
    u16* __restrict__ ctx)
{
    __shared__ u16 Kl[2][KVB*64];
    __shared__ u16 Vl[2][KVB*64];

    const int tid  = threadIdx.x;
    const int lane = tid & 63;
    const int wv   = tid >> 6;
    const int l15  = lane & 15;
    const int lg   = lane >> 4;

    const int d0 = blockIdx.y * 8 + blockIdx.x;
    const int bh = (d0 & 7) * 16 + (d0 >> 6);
    const int qt = (d0 >> 3) & 7;
    const int b  = bh >> 4;
    const int h  = bh & 15;
    const int qbase = qt * 128;
    const size_t bhOff = (size_t)bh * (SEQ*DH);

    const int rS = tid >> 3;
    const int cS = (tid & 7) ^ (rS & 7);
    const u16* kSrc = kh + bhOff + (size_t)rS*DH  + cS*8;
    const u16* vSrc = vt + bhOff + (size_t)rS*SEQ + cS*8;
    const int ldst = wv * 512;

    bf16x8 aq[2][2];
    #pragma unroll
    for (int fq = 0; fq < 2; ++fq)
        #pragma unroll
        for (int kk = 0; kk < 2; ++kk)
            aq[fq][kk] = *reinterpret_cast<const bf16x8*>(
                qh + bhOff + (size_t)(qbase + wv*32 + fq*16 + l15)*DH + kk*32 + lg*8);

    f32x4 o[2][4];
    float mrun[2], lrun[2];
    #pragma unroll
    for (int fq = 0; fq < 2; ++fq) {
        #pragma unroll
        for (int fd = 0; fd < 4; ++fd) o[fq][fd] = (f32x4){0.f,0.f,0.f,0.f};
        mrun[fq] = -1e30f; lrun[fq] = 0.f;
    }

    const int co0 = ((lg)     ^ (l15 & 7)) << 4;
    const int co1 = ((4 + lg) ^ (l15 & 7)) << 4;
    const float* mPtrT = mask + (size_t)b*SEQ + lg*4;

    auto stage = [&](int buf, int kt) {
        const int jb = kt * KVB;
        GLDS16(kSrc + (size_t)jb*DH,        &Kl[buf][ldst]);
        GLDS16(kSrc + (size_t)(jb+32)*DH,   &Kl[buf][2048 + ldst]);
        GLDS16(vSrc + jb,                   &Vl[buf][ldst]);
        GLDS16(vSrc + 32*SEQ + jb,          &Vl[buf][2048 + ldst]);
    };

    stage(0, 0);
    int cur = 0;

    for (int kt = 0; kt < 16; ++kt) {
        __syncthreads();
        if (kt + 1 < 16) stage(cur ^ 1, kt + 1);
        const int jb = kt * KVB;

        f32x4 sc[2][4];
        const char* kb = reinterpret_cast<const char*>(&Kl[cur][0]) + l15*128;
        #pragma unroll
        for (int fn = 0; fn < 4; ++fn) {
            bf16x8 k0 = *reinterpret_cast<const bf16x8*>(kb + fn*2048 + co0);
            bf16x8 k1 = *reinterpret_cast<const bf16x8*>(kb + fn*2048 + co1);
            #pragma unroll
            for (int fq = 0; fq < 2; ++fq) {
                f32x4 t = __builtin_amdgcn_mfma_f32_16x16x32_bf16(k0, aq[fq][0],
                            (f32x4){0.f,0.f,0.f,0.f}, 0, 0, 0);
                sc[fq][fn] = __builtin_amdgcn_mfma_f32_16x16x32_bf16(k1, aq[fq][1], t, 0, 0, 0);
            }
        }
        #pragma unroll
        for (int fn = 0; fn < 4; ++fn) {
            float4 mk = *reinterpret_cast<const float4*>(mPtrT + jb + fn*16);
            const float mkf[4] = {mk.x, mk.y, mk.z, mk.w};
            #pragma unroll
            for (int fq = 0; fq < 2; ++fq)
                #pragma unroll
                for (int r = 0; r < 4; ++r)
                    sc[fq][fn][r] = fmaf(mkf[r], L2E, sc[fq][fn][r]);
        }
        float mx[2];
        #pragma unroll
        for (int fq = 0; fq < 2; ++fq) {
            float m01 = fmaxf(fmaxf(sc[fq][0][0], sc[fq][0][1]),
                              fmaxf(sc[fq][0][2], sc[fq][0][3]));
            #pragma unroll
            for (int fn = 1; fn < 4; ++fn)
                m01 = fmaxf(m01, fmaxf(fmaxf(sc[fq][fn][0], sc[fq][fn][1]),
                                       fmaxf(sc[fq][fn][2], sc[fq][fn][3])));
            m01 = fmaxf(m01, __shfl_xor(m01, 16));
            m01 = fmaxf(m01, __shfl_xor(m01, 32));
            mx[fq] = m01;
        }
        int need = (mx[0] > mrun[0] + 11.5f) | (mx[1] > mrun[1] + 11.5f);
        if (__any(need)) {
            #pragma unroll
            for (int fq = 0; fq < 2; ++fq) {
                const float mn  = fmaxf(mrun[fq], mx[fq]);
                const float scl = fexp2(mrun[fq] - mn);
                mrun[fq] = mn;
                lrun[fq] *= scl;
                float s4[4];
                #pragma unroll
                for (int r = 0; r < 4; ++r) s4[r] = __shfl(scl, lg*4 + r);
                #pragma unroll
                for (int fd = 0; fd < 4; ++fd)
                    #pragma unroll
                    for (int r = 0; r < 4; ++r) o[fq][fd][r] *= s4[r];
            }
        }
        u32 pw[2][2][4];
        #pragma unroll
        for (int fq = 0; fq < 2; ++fq) {
            float rs = 0.f;
            #pragma unroll
            for (int fn = 0; fn < 4; ++fn) {
                const float p0 = fexp2(sc[fq][fn][0] - mrun[fq]);
                const float p1 = fexp2(sc[fq][fn][1] - mrun[fq]);
                const float p2 = fexp2(sc[fq][fn][2] - mrun[fq]);
                const float p3 = fexp2(sc[fq][fn][3] - mrun[fq]);
                rs += (p0 + p1) + (p2 + p3);
                u32 wA, wB;
                asm("v_cvt_pk_bf16_f32 %0, %1, %2" : "=v"(wA) : "v"(p0), "v"(p1));
                asm("v_cvt_pk_bf16_f32 %0, %1, %2" : "=v"(wB) : "v"(p2), "v"(p3));
                pw[fq][fn >> 1][(fn & 1)*2 + 0] = wA;
                pw[fq][fn >> 1][(fn & 1)*2 + 1] = wB;
            }
            rs += __shfl_xor(rs, 16);
            rs += __shfl_xor(rs, 32);
            lrun[fq] += rs;
        }
        bf16x8 pa[2][2];
        #pragma unroll
        for (int fq = 0; fq < 2; ++fq)
            #pragma unroll
            for (int kk = 0; kk < 2; ++kk) {
                union { u32 w[4]; bf16x8 v; } u;
                u.w[0] = pw[fq][kk][0]; u.w[1] = pw[fq][kk][1];
                u.w[2] = pw[fq][kk][2]; u.w[3] = pw[fq][kk][3];
                pa[fq][kk] = u.v;
            }
        const char* vb = reinterpret_cast<const char*>(&Vl[cur][0]) + l15*128;
        #pragma unroll
        for (int kk = 0; kk < 2; ++kk) {
            const int coff = kk ? co1 : co0;
            #pragma unroll
            for (int fd = 0; fd < 4; ++fd) {
                bf16x8 vf = *reinterpret_cast<const bf16x8*>(vb + fd*2048 + coff);
                #pragma unroll
                for (int fq = 0; fq < 2; ++fq)
                    o[fq][fd] = __builtin_amdgcn_mfma_f32_16x16x32_bf16(pa[fq][kk], vf, o[fq][fd], 0, 0, 0);
            }
        }
        cur ^= 1;
    }

    #pragma unroll
    for (int fq = 0; fq < 2; ++fq) {
        const float linv = 1.0f / lrun[fq];
        float inv4[4];
        #pragma unroll
        for (int r = 0; r < 4; ++r) inv4[r] = __shfl(linv, lg*4 + r);
        #pragma unroll
        for (int r = 0; r < 4; ++r) {
            const int s = qbase + wv*32 + fq*16 + lg*4 + r;
            #pragma unroll
            for (int fd = 0; fd < 4; ++fd) {
                const int d = fd*16 + l15;
                ctx[((size_t)(s*BSZ + b))*EMB + h*DH + d] = f2bf(o[fq][fd][r] * inv4[r]);
            }
        }
    }
}

extern "C" void kernel_launch(void* const* d_in, const int* in_sizes, int n_in,
                              void* d_out, int out_size, void* d_ws, size_t ws_size,
                              hipStream_t stream) {
    const float* x    = (const float*)d_in[0];
    const float* mask = (const float*)d_in[1];
    const float* w_q  = (const float*)d_in[2];
    const float* w_k  = (const float*)d_in[3];
    const float* w_v  = (const float*)d_in[4];
    const float* w_o  = (const float*)d_in[5];
    const float* b_o  = (const float*)d_in[6];

    char* ws = (char*)d_ws;
    u16* xb  = (u16*)(ws);                        // 16 MB
    u16* wT  = (u16*)(ws + ((size_t)16 << 20));   // 8 MB
    u16* qh  = (u16*)(ws + ((size_t)24 << 20));   // 16 MB
    u16* kh  = (u16*)(ws + ((size_t)40 << 20));   // 16 MB
    u16* vt  = (u16*)(ws + ((size_t)56 << 20));   // 16 MB (V transposed + key-permuted)
    u16* vh  = (u16*)(ws + ((size_t)72 << 20));   // 16 MB
    u16* ctx = vh;                                // vh dead after vtrans
    float* outp = (float*)d_out;

    cvt_k<<<6144, 256, 0, stream>>>(x, w_q, w_k, w_v, w_o, xb, wT);
    gemm_t<0><<<768, 256, 0, stream>>>(xb, wT, nullptr, qh, kh, vh, nullptr);
    vtrans_k<<<dim3(16, 128), 256, 0, stream>>>(vh, x, vt);
    attn_k<<<dim3(8, 128), 256, 0, stream>>>(qh, kh, vt, mask, ctx);
    gemm_t<1><<<256, 256, 0, stream>>>(ctx, wT + (size_t)3*1048576, b_o,
                                       nullptr, nullptr, nullptr, outp);
}